// Round 12
// baseline (778.559 us; speedup 1.0000x reference)
//
#include <hip/hip_runtime.h>
#include <math.h>

typedef __attribute__((ext_vector_type(8))) _Float16 half8;
typedef __attribute__((ext_vector_type(4))) float f32x4;
typedef unsigned long long u64;

#define BK 32

#define EPI_NAT  0
#define EPI_TR   1
#define EPI_FCD  2
#define EPI_OUT  3
#define EPI_PART 4

typedef const __attribute__((address_space(1))) void* gas1;
typedef __attribute__((address_space(3))) void* las3;

template<int I> struct ic { static constexpr int v = I; };

__device__ __forceinline__ void gl16(const void* g, void* l) {
    __builtin_amdgcn_global_load_lds((gas1)g, (las3)l, 16, 0, 0);
}
template<int N> __device__ __forceinline__ void vwait() {
    asm volatile("s_waitcnt vmcnt(%0)" :: "n"(N) : "memory");
}
__device__ __forceinline__ void barx() {
    asm volatile("" ::: "memory");
    __builtin_amdgcn_s_barrier();
    asm volatile("" ::: "memory");
}

// ============ pool kernel v3: A via LDS (gl16, swizzled), B DIRECT global->VGPR ============
// B (actT [(col)][K]) is already in MFMA B-frag layout: lane(lm,lg) reads
// B[f0+wf*64+j*16+lm][ks*32+lg*8] -> 16 rows x 64B contiguous per instr (L1/L2-served).
// 3-deep register pipeline, static buffer indices (no scratch).
template<int TBM, int OCC>
__global__ __launch_bounds__(256, OCC) void pool3_k(
    const _Float16* __restrict__ Aw, const _Float16* __restrict__ Bw,
    _Float16* __restrict__ Cp, int M, int Np, u64 c_rs)
{
    constexpr int FM = TBM / 32;      // wave m-frags (WM=2)
    constexpr int LA = TBM / 64;      // gl16 instrs per stage (wave-wide)

    __shared__ _Float16 sA[3][TBM][BK];

    const int t  = threadIdx.x;
    const int m0 = blockIdx.y * TBM;
    const int f0 = blockIdx.x * 128;
    const int lane = t & 63;
    const int wid  = t >> 6;
    const int wm = wid >> 1;
    const int wf = wid & 1;
    const int lm = lane & 15;
    const int lg = lane >> 4;

    f32x4 acc[FM][4];
    #pragma unroll
    for (int i = 0; i < FM; ++i)
        #pragma unroll
        for (int j = 0; j < 4; ++j)
            acc[i][j] = (f32x4)0.0f;

    half8 bB0[4], bB1[4], bB2[4];

    const _Float16* Bbase = Bw + (u64)(f0 + wf * 64 + lm) * Np + lg * 8;

    auto stageA = [&](int buf, int ks) {
        #pragma unroll
        for (int j = 0; j < LA; ++j) {
            int c   = t + j * 256;
            int row = c >> 2;
            int sw  = ((c & 3) ^ ((row >> 1) & 3)) * 8;   // pre-swizzled source chunk
            int rc  = m0 + row; if (rc >= M) rc = M - 1;
            gl16(Aw + (u64)rc * Np + ks * BK + sw,
                 (_Float16*)&sA[buf][0][0] + (u64)c * 8);  // linear dest
        }
    };
    auto loadB = [&](auto bufc, int ks) {
        constexpr int BUF = decltype(bufc)::v;
        #pragma unroll
        for (int j = 0; j < 4; ++j) {
            half8 v = *(const half8*)(Bbase + (u64)j * 16 * Np + ks * BK);
            if constexpr (BUF == 0) bB0[j] = v;
            else if constexpr (BUF == 1) bB1[j] = v;
            else bB2[j] = v;
        }
    };
    auto computeT = [&](auto bufc) {
        constexpr int BUF = decltype(bufc)::v;
        const int sa = (lg ^ ((lm >> 1) & 3)) * 8;        // un-swizzle on read
        half8 af[FM];
        #pragma unroll
        for (int i = 0; i < FM; ++i)
            af[i] = *(const half8*)&sA[BUF][wm * (FM * 16) + i * 16 + lm][sa];
        #pragma unroll
        for (int i = 0; i < FM; ++i)
            #pragma unroll
            for (int j = 0; j < 4; ++j) {
                half8 bv;
                if constexpr (BUF == 0) bv = bB0[j];
                else if constexpr (BUF == 1) bv = bB1[j];
                else bv = bB2[j];
                acc[i][j] = __builtin_amdgcn_mfma_f32_16x16x32_f16(af[i], bv, acc[i][j], 0, 0, 0);
            }
    };

    const int ke = Np / BK;
    auto dostep = [&](auto bufc, int ks) {
        constexpr int BUF = decltype(bufc)::v;
        int rem = ke - ks;
        if (rem >= 3)      vwait<2 * (LA + 4)>();
        else if (rem == 2) vwait<LA + 4>();
        else               vwait<0>();
        barx();
        computeT(bufc);
        barx();
        if (ks + 3 < ke) { stageA(BUF, ks + 3); loadB(bufc, ks + 3); }
    };

    stageA(0, 0); loadB(ic<0>{}, 0);
    if (1 < ke) { stageA(1, 1); loadB(ic<1>{}, 1); }
    if (2 < ke) { stageA(2, 2); loadB(ic<2>{}, 2); }
    int ks = 0;
    while (true) {
        dostep(ic<0>{}, ks); if (++ks >= ke) break;
        dostep(ic<1>{}, ks); if (++ks >= ke) break;
        dostep(ic<2>{}, ks); if (++ks >= ke) break;
    }

    #pragma unroll
    for (int j = 0; j < 4; ++j) {
        int fl = f0 + wf * 64 + j * 16 + lm;
        #pragma unroll
        for (int i = 0; i < FM; ++i) {
            #pragma unroll
            for (int r = 0; r < 4; ++r) {
                int m = m0 + wm * (FM * 16) + i * 16 + lg * 4 + r;
                if (m < M)
                    Cp[(u64)m * c_rs + fl] = (_Float16)acc[i][j][r];
            }
        }
    }
}

// ============ general kernel (sconv / fc) ============
// AMODE: 1 sconv gather (idx via LDS), 2 sconv0 (Fi=3, nk=1),
//        3 fc, 4 fc-enc split-K, 5 sconv rows-folded [Wd3]
template<int AMODE, int EPI, int TBM, int TBF, int WM, int WF>
__global__ __launch_bounds__(256) void gemm_k(
    const _Float16* __restrict__ Aw, u64 a_rs,
    const int* __restrict__ idx, int FiLog,
    const _Float16* __restrict__ Bw,
    const float* __restrict__ bias,
    void* __restrict__ Cp, u64 c_rs, int Mp_out,
    int M, int Np, int F, int flags, int ksp)   // flags: bit0 ELU, bit1 zeroLast
{
    constexpr int FM = TBM / WM / 16;
    constexpr int FF = TBF / WF / 16;
    constexpr int LPS_A = TBM / 64;
    constexpr bool BSM = (TBF < 64);
    constexpr int LPS_B = BSM ? 0 : TBF / 64;
    constexpr int LW0 = LPS_A + (BSM ? 1 : LPS_B);
    constexpr int LWX = LPS_A + LPS_B;
    constexpr int NI = (AMODE == 1) ? TBM : 2;

    __shared__ _Float16 sA[3][TBM][BK];
    __shared__ _Float16 sB[3][TBF][BK];
    __shared__ int sIdx[NI][9];

    const int t  = threadIdx.x;
    const int b  = blockIdx.z;
    const int m0 = blockIdx.y * TBM;
    const int f0 = blockIdx.x * TBF;
    const int lane = t & 63;
    const int wid  = t >> 6;
    const int wm = wid / WF;
    const int wf = wid % WF;
    const int lm = lane & 15;
    const int lg = lane >> 4;
    const int Fi = 1 << FiLog;

    f32x4 acc[FM][FF];
    #pragma unroll
    for (int i = 0; i < FM; ++i)
        #pragma unroll
        for (int j = 0; j < FF; ++j)
            acc[i][j] = (f32x4)0.0f;

    if constexpr (AMODE == 1) {
        for (int i = t; i < TBM * 9; i += 256) {
            int r = i / 9, k = i - r * 9;
            int rc = m0 + r; if (rc >= M) rc = M - 1;
            sIdx[r][k] = idx[rc * 9 + k];
        }
        __syncthreads();
    } else if constexpr (AMODE == 5) {
        if (t < 18) {
            int r = t / 9, k = t - r * 9;
            sIdx[r][k] = idx[((m0 >> 6) + r) * 9 + k];
        }
        __syncthreads();
    }

    auto stage = [&](int buf, int ks) {
        if constexpr (AMODE != 2) {
            #pragma unroll
            for (int j = 0; j < LPS_A; ++j) {
                int c   = t + j * 256;
                int row = c >> 2;
                int sw  = ((c & 3) ^ ((row >> 1) & 3)) * 8;   // pre-swizzled source chunk
                int col = ks * BK + sw;
                const _Float16* src;
                if constexpr (AMODE == 3) {
                    int rc = m0 + row; if (rc >= M) rc = M - 1;
                    src = Aw + (u64)rc * Np + col;
                } else if constexpr (AMODE == 1) {
                    int k = col >> FiLog, fi = col & (Fi - 1);
                    src = Aw + (u64)sIdx[row][k] * a_rs + b * Fi + fi;
                } else if constexpr (AMODE == 4) {
                    int k = col >> FiLog, fi = col & (Fi - 1);
                    src = Aw + (u64)k * a_rs + (m0 + row) * Fi + fi;
                } else {  // 5
                    int k = col >> FiLog, fi = col & (Fi - 1);
                    int bb = (m0 + row) & 63;
                    src = Aw + (u64)sIdx[row >> 6][k] * a_rs + bb * Fi + fi;
                }
                gl16(src, &sA[buf][row][(c & 3) * 8]);   // linear dest
            }
        }
        if constexpr (!BSM) {
            #pragma unroll
            for (int j = 0; j < LPS_B; ++j) {
                int c   = t + j * 256;
                int row = c >> 2;
                int sw  = ((c & 3) ^ ((row >> 1) & 3)) * 8;
                gl16(Bw + (u64)(f0 + row) * Np + ks * BK + sw, &sB[buf][row][(c & 3) * 8]);
            }
        } else {
            if (wid == 0) {
                int c   = t;
                int row = c >> 2;
                int sw  = ((c & 3) ^ ((row >> 1) & 3)) * 8;
                gl16(Bw + (u64)(f0 + row) * Np + ks * BK + sw, &sB[buf][row][(c & 3) * 8]);
            }
        }
    };

    auto compute = [&](int buf) {
        const int sa = (lg ^ ((lm >> 1) & 3)) * 8;   // un-swizzle on read
        half8 af[FM], bf[FF];
        #pragma unroll
        for (int i = 0; i < FM; ++i)
            af[i] = *(const half8*)&sA[buf][wm * (FM * 16) + i * 16 + lm][sa];
        #pragma unroll
        for (int j = 0; j < FF; ++j)
            bf[j] = *(const half8*)&sB[buf][wf * (FF * 16) + j * 16 + lm][sa];
        #pragma unroll
        for (int i = 0; i < FM; ++i)
            #pragma unroll
            for (int j = 0; j < FF; ++j)
                acc[i][j] = __builtin_amdgcn_mfma_f32_16x16x32_f16(af[i], bf[j], acc[i][j], 0, 0, 0);
    };

    if constexpr (AMODE == 2) {
        stage(0, 0);   // B only
        {
            int row = t >> 1;
            int base = (t & 1) * 16;
            int rg = m0 + row;
            #pragma unroll
            for (int q = 0; q < 16; ++q) {
                int n = base + q;
                _Float16 val = (_Float16)0.f;
                if (rg < M && n < 27) {
                    int k = n / 3, fi = n - k * 3;
                    val = Aw[(u64)idx[rg * 9 + k] * a_rs + b * 3 + fi];
                }
                int ch = (n >> 3) ^ ((row >> 1) & 3);
                sA[0][row][ch * 8 + (n & 7)] = val;   // store swizzled
            }
        }
        __syncthreads();
        compute(0);
    } else {
        int kb = 0, ke = Np / BK;
        if constexpr (AMODE == 4) { kb = b * ksp; ke = kb + ksp; }
        stage(0, kb);
        if (kb + 1 < ke) stage(1, kb + 1);
        if (kb + 2 < ke) stage(2, kb + 2);
        int cur = 0;
        for (int ks = kb; ks < ke; ++ks) {
            int rem = ke - ks;
            if (rem >= 3) {
                if constexpr (LW0 == LWX) vwait<2 * LW0>();
                else { if (wid == 0) vwait<2 * LW0>(); else vwait<2 * LWX>(); }
            } else if (rem == 2) {
                if constexpr (LW0 == LWX) vwait<LW0>();
                else { if (wid == 0) vwait<LW0>(); else vwait<LWX>(); }
            } else {
                vwait<0>();
            }
            barx();
            compute(cur);
            barx();
            if (ks + 3 < ke) stage(cur, ks + 3);
            cur = (cur == 2) ? 0 : cur + 1;
        }
    }

    #pragma unroll
    for (int j = 0; j < FF; ++j) {
        int fl = f0 + wf * (FF * 16) + j * 16 + lm;
        float bv = 0.f;
        if (bias != nullptr && fl < F) bv = bias[fl];
        #pragma unroll
        for (int i = 0; i < FM; ++i) {
            #pragma unroll
            for (int r = 0; r < 4; ++r) {
                int m = m0 + wm * (FM * 16) + i * 16 + lg * 4 + r;
                float v = acc[i][j][r] + bv;
                if (flags & 1) v = (v > 0.f) ? v : expm1f(v);
                if constexpr (EPI == EPI_NAT) {
                    if (m < M && fl < F)
                        ((_Float16*)Cp)[(u64)m * c_rs + fl] = (_Float16)v;
                } else if constexpr (EPI == EPI_TR) {
                    if (m < Mp_out && fl < F) {
                        float o = (m < M && !((flags & 2) && m == M - 1)) ? v : 0.f;
                        ((_Float16*)Cp)[(u64)b * c_rs + (u64)fl * Mp_out + m] = (_Float16)o;
                    }
                } else if constexpr (EPI == EPI_FCD) {
                    if (m < M && fl < F)
                        ((_Float16*)Cp)[((u64)m * 256 + (fl & 255)) * 32 + (fl >> 8)] = (_Float16)v;
                } else if constexpr (EPI == EPI_PART) {
                    if (m < M && fl < F)
                        ((float*)Cp)[(u64)b * c_rs + (u64)m * F + fl] = v;
                } else {  // EPI_OUT (rows folded: m = v*64+b)
                    if (m < M && fl < F) {
                        int vo = m >> 6, bb = m & 63;
                        float o = ((flags & 2) && vo == Mp_out - 1) ? 0.f : v;
                        ((float*)Cp)[((u64)bb * Mp_out + vo) * 3 + fl] = o;
                    }
                }
            }
        }
    }
}

// ---- fused weight conversion ----
struct CvtPtrs { const float* p[18]; };

constexpr int CV_R[18]  = {1257,5024,315,1257,80,315,21,80,  64,64,128,256,256,5376,128,64,64,16};
constexpr int CV_N[18]  = {5024,1257,1257,315,315,80,80,21,  27,576,576,1152,5376,256,2304,1152,576,576};
constexpr int CV_NP[18] = {5120,1280,1280,320,320,96,96,32,  32,576,576,1152,5376,256,2304,1152,576,576};
constexpr int CV_F[18]  = {0,0,0,0,0,0,0,0,  64,64,128,256,256,5376,128,64,64,3};

constexpr u64 cv_elems(int i) { return (u64)CV_R[i] * CV_NP[i]; }
constexpr u64 cv_off(int i) { u64 o = 0; for (int j = 0; j < i; ++j) o += (cv_elems(j) + 255) & ~(u64)255; return o; }
constexpr int cv_blk(int i) { return (int)((cv_elems(i) + 255) >> 8); }
constexpr int cv_start(int i) { int s = 0; for (int j = 0; j < i; ++j) s += cv_blk(j); return s; }

__global__ __launch_bounds__(256) void cvt_all(CvtPtrs ps, _Float16* __restrict__ dst)
{
    const int bx = blockIdx.x, t = threadIdx.x;
    #pragma unroll
    for (int i = 0; i < 18; ++i) {
        if (bx >= cv_start(i) && bx < cv_start(i + 1)) {
            const u64 e = (u64)(bx - cv_start(i)) * 256 + t;
            if (e < cv_elems(i)) {
                const int NP = CV_NP[i], N = CV_N[i], Fo = CV_F[i];
                int row = (int)(e / (u64)NP);
                int col = (int)(e - (u64)row * NP);
                float v = 0.f;
                const float* s = ps.p[i];
                if (Fo == 0) { if (col < N) v = s[(u64)row * N + col]; }
                else         { if (col < N && row < Fo) v = s[(u64)col * Fo + row]; }
                dst[cv_off(i) + e] = (_Float16)v;
            }
        }
    }
}

__global__ void cvt_x(const float* __restrict__ src, _Float16* __restrict__ dst)
{
    int i = blockIdx.x * 256 + threadIdx.x;
    if (i >= 64 * 5024 * 3) return;
    int v = i / 192;
    int r = i - v * 192;
    int b = r / 3, c = r - b * 3;
    dst[i] = (_Float16)src[((u64)b * 5024 + v) * 3 + c];
}

__global__ void reduce_fce(const float* __restrict__ part, const float* __restrict__ bias,
                           _Float16* __restrict__ z)
{
    int i = blockIdx.x * 256 + threadIdx.x;  // 64*256
    int fl = i & 255;
    float s = bias[fl];
    #pragma unroll
    for (int p = 0; p < 8; ++p) s += part[(u64)p * 16384 + i];
    z[i] = (_Float16)s;
}

extern "C" void kernel_launch(void* const* d_in, const int* in_sizes, int n_in,
                              void* d_out, int out_size, void* d_ws, size_t ws_size,
                              hipStream_t stream)
{
    const float* x  = (const float*)d_in[0];
    const int* s0 = (const int*)d_in[1];
    const int* s1 = (const int*)d_in[2];
    const int* s2 = (const int*)d_in[3];
    const int* s3 = (const int*)d_in[4];
    const float* be0 = (const float*)d_in[14];
    const float* be1 = (const float*)d_in[16];
    const float* be2 = (const float*)d_in[18];
    const float* be3 = (const float*)d_in[20];
    const float* fceb = (const float*)d_in[22];
    const float* fcdb = (const float*)d_in[24];
    const float* bd0 = (const float*)d_in[26];
    const float* bd1 = (const float*)d_in[28];
    const float* bd2 = (const float*)d_in[30];
    const float* bd3 = (const float*)d_in[32];

    _Float16* W = (_Float16*)d_ws;
    size_t off = 0;
    auto alloc = [&](size_t e) { size_t o = off; off += (e + 255) & ~(size_t)255; return o; };

    const size_t oActV = alloc((size_t)5024 * 4096);   // [vertex][(b,f)]
    const size_t oActT = alloc((size_t)4096 * 5120);   // [(b,f)][vertex_padded]
    const size_t oZ    = alloc((size_t)64 * 256);
    const size_t oPart = alloc((size_t)8 * 64 * 256 * 2);   // fp32 partials (fce)
    const size_t oU3in = alloc((size_t)16384 * 32);
    const size_t oXp   = alloc((size_t)5024 * 192);
    const size_t oCvt  = alloc((size_t)(cv_off(17) + ((cv_elems(17) + 255) & ~(u64)255)));
    auto wofs = [&](int i) { return oCvt + (size_t)cv_off(i); };

    // ---- conversions ----
    cvt_x<<<dim3((64 * 5024 * 3 + 255) / 256), 256, 0, stream>>>(x, W + oXp);
    {
        CvtPtrs ps;
        ps.p[0] = (const float*)d_in[5];   // D0
        ps.p[1] = (const float*)d_in[6];   // U0
        ps.p[2] = (const float*)d_in[7];   // D1
        ps.p[3] = (const float*)d_in[8];   // U1
        ps.p[4] = (const float*)d_in[9];   // D2
        ps.p[5] = (const float*)d_in[10];  // U2
        ps.p[6] = (const float*)d_in[11];  // D3
        ps.p[7] = (const float*)d_in[12];  // U3
        ps.p[8] = (const float*)d_in[13];  // We0
        ps.p[9] = (const float*)d_in[15];  // We1
        ps.p[10] = (const float*)d_in[17]; // We2
        ps.p[11] = (const float*)d_in[19]; // We3
        ps.p[12] = (const float*)d_in[21]; // fceW
        ps.p[13] = (const float*)d_in[23]; // fcdW
        ps.p[14] = (const float*)d_in[25]; // Wd0
        ps.p[15] = (const float*)d_in[27]; // Wd1
        ps.p[16] = (const float*)d_in[29]; // Wd2
        ps.p[17] = (const float*)d_in[31]; // Wd3
        cvt_all<<<dim3(cv_start(18)), 256, 0, stream>>>(ps, W + oCvt);
    }
    hipMemsetAsync(W + oU3in, 0, (size_t)16384 * 32 * sizeof(_Float16), stream);

    #define GEMM(AM, EP, BM_, BF_, WM_, WF_, gx, gy, gz, Aw_, ars_, idx_, FiL_, Bw_, bias_, Cp_, crs_, Mp_, M_, Np_, F_, fl_, ksp_) \
        gemm_k<AM, EP, BM_, BF_, WM_, WF_><<<dim3(gx, gy, gz), 256, 0, stream>>>( \
            Aw_, ars_, idx_, FiL_, Bw_, bias_, Cp_, crs_, Mp_, M_, Np_, F_, fl_, ksp_)
    #define POOL(TBM_, OCC_, gx, gy, Aw_, Bw_, Cp_, M_, Np_, crs_) \
        pool3_k<TBM_, OCC_><<<dim3(gx, gy), 256, 0, stream>>>(Aw_, Bw_, Cp_, M_, Np_, crs_)

    // ---- encoder ----
    GEMM(2, EPI_TR, 128, 64, 2, 2, 1, 40, 64, W + oXp, 192, s0, 0,
         W + wofs(8), be0, W + oActT, (u64)64 * 5120, 5120, 5024, 32, 64, 3, 0);
    POOL(64, 4, 32, 20, W + wofs(0), W + oActT, W + oActV, 1257, 5120, 4096);
    GEMM(1, EPI_TR, 128, 64, 2, 2, 1, 10, 64, W + oActV, 4096, s1, 6,
         W + wofs(9), be1, W + oActT, (u64)64 * 1280, 1280, 1257, 576, 64, 3, 0);
    POOL(64, 4, 32, 5, W + wofs(2), W + oActT, W + oActV, 315, 1280, 4096);
    GEMM(1, EPI_TR, 128, 64, 2, 2, 2, 3, 64, W + oActV, 4096, s2, 6,
         W + wofs(10), be2, W + oActT, (u64)128 * 320, 320, 315, 576, 128, 3, 0);
    POOL(64, 4, 64, 2, W + wofs(4), W + oActT, W + oActV, 80, 320, 8192);
    GEMM(1, EPI_TR, 128, 64, 2, 2, 4, 1, 64, W + oActV, 8192, s3, 7,
         W + wofs(11), be3, W + oActT, (u64)256 * 96, 96, 80, 1152, 256, 3, 0);
    POOL(64, 4, 128, 1, W + wofs(6), W + oActT, W + oActV, 21, 96, 16384);
    // ---- bottleneck ----
    GEMM(4, EPI_PART, 64, 64, 2, 2, 4, 1, 8, W + oActV, 16384, nullptr, 8,
         W + wofs(12), nullptr, W + oPart, (u64)64 * 256, 0, 64, 5376, 256, 0, 21);
    reduce_fce<<<dim3(64), 256, 0, stream>>>((const float*)(W + oPart), fceb, W + oZ);
    GEMM(3, EPI_FCD, 64, 128, 2, 2, 42, 1, 1, W + oZ, 0, nullptr, 0,
         W + wofs(13), fcdb, W + oU3in, 0, 0, 64, 256, 5376, 0, 0);
    // ---- decoder ----
    POOL(64, 4, 128, 2, W + wofs(7), W + oU3in, W + oActV, 80, 32, 16384);
    GEMM(1, EPI_TR, 128, 64, 2, 2, 2, 1, 64, W + oActV, 16384, s3, 8,
         W + wofs(14), bd0, W + oActT, (u64)128 * 96, 96, 80, 2304, 128, 3, 0);
    POOL(64, 4, 64, 5, W + wofs(5), W + oActT, W + oActV, 315, 96, 8192);
    GEMM(1, EPI_TR, 128, 64, 2, 2, 1, 3, 64, W + oActV, 8192, s2, 7,
         W + wofs(15), bd1, W + oActT, (u64)64 * 320, 320, 315, 1152, 64, 3, 0);
    POOL(64, 4, 32, 20, W + wofs(3), W + oActT, W + oActV, 1257, 320, 4096);
    GEMM(1, EPI_TR, 128, 64, 2, 2, 1, 10, 64, W + oActV, 4096, s1, 6,
         W + wofs(16), bd2, W + oActT, (u64)64 * 1280, 1280, 1257, 576, 64, 3, 0);
    POOL(128, 3, 32, 40, W + wofs(1), W + oActT, W + oActV, 5024, 1280, 4096);
    GEMM(5, EPI_OUT, 128, 16, 4, 1, 1, 2512, 1, W + oActV, 4096, s0, 6,
         W + wofs(17), bd3, d_out, 0, 5024, 321536, 576, 3, 2, 0);
    #undef GEMM
    #undef POOL
}

// Round 13
// 614.271 us; speedup vs baseline: 1.2675x; 1.2675x over previous
//
#include <hip/hip_runtime.h>
#include <math.h>

typedef __attribute__((ext_vector_type(8))) _Float16 half8;
typedef __attribute__((ext_vector_type(4))) float f32x4;
typedef unsigned long long u64;

#define BK 32

#define EPI_NAT  0
#define EPI_TR   1
#define EPI_FCD  2
#define EPI_OUT  3
#define EPI_PART 4

typedef const __attribute__((address_space(1))) void* gas1;
typedef __attribute__((address_space(3))) void* las3;

__device__ __forceinline__ void gl16(const void* g, void* l) {
    __builtin_amdgcn_global_load_lds((gas1)g, (las3)l, 16, 0, 0);
}
template<int N> __device__ __forceinline__ void vwait() {
    asm volatile("s_waitcnt vmcnt(%0)" :: "n"(N) : "memory");
}
__device__ __forceinline__ void barx() {
    asm volatile("" ::: "memory");
    __builtin_amdgcn_s_barrier();
    asm volatile("" ::: "memory");
}

// ============ pool kernel: 256 thr, 4 waves (2x2), TBMx128 tile, BK=32 ============
// 4-deep buffers -> ONE barrier per K-step: step ks reads buf ks&3 and stages into
// (ks+3)&3 == (ks-1)&3, whose last reader finished before this step's barrier.
template<int TBM, int OCC>
__global__ __launch_bounds__(256, OCC) void pool2_k(
    const _Float16* __restrict__ Aw, const _Float16* __restrict__ Bw,
    _Float16* __restrict__ Cp, int M, int Np, u64 c_rs)
{
    constexpr int FM  = TBM / 32;          // wave m-frags (WM=2)
    constexpr int LPS = TBM / 64 + 2;      // gl16 per thread per stage

    __shared__ _Float16 sA[4][TBM][BK];
    __shared__ _Float16 sB[4][128][BK];

    const int t  = threadIdx.x;
    const int m0 = blockIdx.y * TBM;
    const int f0 = blockIdx.x * 128;
    const int lane = t & 63;
    const int wid  = t >> 6;
    const int wm = wid >> 1;
    const int wf = wid & 1;
    const int lm = lane & 15;
    const int lg = lane >> 4;

    f32x4 acc[FM][4];
    #pragma unroll
    for (int i = 0; i < FM; ++i)
        #pragma unroll
        for (int j = 0; j < 4; ++j)
            acc[i][j] = (f32x4)0.0f;

    auto stage = [&](int buf, int ks) {
        #pragma unroll
        for (int j = 0; j < TBM / 64; ++j) {
            int c   = t + j * 256;
            int row = c >> 2;
            int sw  = ((c & 3) ^ ((row >> 1) & 3)) * 8;   // pre-swizzled source chunk
            int rc  = m0 + row; if (rc >= M) rc = M - 1;
            gl16(Aw + (u64)rc * Np + ks * BK + sw,
                 (_Float16*)&sA[buf][0][0] + (u64)c * 8);  // linear dest
        }
        #pragma unroll
        for (int j = 0; j < 2; ++j) {
            int c   = t + j * 256;
            int row = c >> 2;
            int sw  = ((c & 3) ^ ((row >> 1) & 3)) * 8;
            gl16(Bw + (u64)(f0 + row) * Np + ks * BK + sw,
                 (_Float16*)&sB[buf][0][0] + (u64)c * 8);
        }
    };

    auto compute = [&](int buf) {
        const int sa = (lg ^ ((lm >> 1) & 3)) * 8;        // un-swizzle on read
        half8 af[FM], bf[4];
        #pragma unroll
        for (int i = 0; i < FM; ++i)
            af[i] = *(const half8*)&sA[buf][wm * (FM * 16) + i * 16 + lm][sa];
        #pragma unroll
        for (int j = 0; j < 4; ++j)
            bf[j] = *(const half8*)&sB[buf][wf * 64 + j * 16 + lm][sa];
        #pragma unroll
        for (int i = 0; i < FM; ++i)
            #pragma unroll
            for (int j = 0; j < 4; ++j)
                acc[i][j] = __builtin_amdgcn_mfma_f32_16x16x32_f16(af[i], bf[j], acc[i][j], 0, 0, 0);
    };

    const int ke = Np / BK;
    stage(0, 0);
    if (1 < ke) stage(1, 1);
    if (2 < ke) stage(2, 2);
    for (int ks = 0; ks < ke; ++ks) {
        int rem = ke - ks;
        if (rem >= 3)      vwait<2 * LPS>();
        else if (rem == 2) vwait<LPS>();
        else               vwait<0>();
        barx();                                   // single barrier per step
        if (ks + 3 < ke) stage((ks + 3) & 3, ks + 3);
        compute(ks & 3);
    }

    #pragma unroll
    for (int j = 0; j < 4; ++j) {
        int fl = f0 + wf * 64 + j * 16 + lm;
        #pragma unroll
        for (int i = 0; i < FM; ++i) {
            #pragma unroll
            for (int r = 0; r < 4; ++r) {
                int m = m0 + wm * (FM * 16) + i * 16 + lg * 4 + r;
                if (m < M)
                    Cp[(u64)m * c_rs + fl] = (_Float16)acc[i][j][r];
            }
        }
    }
}

// ============ general kernel (sconv / fc), 4-buf single-barrier ============
// AMODE: 1 sconv gather (idx via LDS), 2 sconv0 (Fi=3, nk=1),
//        3 fc, 4 fc-enc split-K, 5 sconv rows-folded [Wd3]
template<int AMODE, int EPI, int TBM, int TBF, int WM, int WF>
__global__ __launch_bounds__(256) void gemm_k(
    const _Float16* __restrict__ Aw, u64 a_rs,
    const int* __restrict__ idx, int FiLog,
    const _Float16* __restrict__ Bw,
    const float* __restrict__ bias,
    void* __restrict__ Cp, u64 c_rs, int Mp_out,
    int M, int Np, int F, int flags, int ksp)   // flags: bit0 ELU, bit1 zeroLast
{
    constexpr int FM = TBM / WM / 16;
    constexpr int FF = TBF / WF / 16;
    constexpr int LPS_A = TBM / 64;
    constexpr bool BSM = (TBF < 64);
    constexpr int LPS_B = BSM ? 0 : TBF / 64;
    constexpr int LW0 = LPS_A + (BSM ? 1 : LPS_B);
    constexpr int LWX = LPS_A + LPS_B;
    constexpr int NI = (AMODE == 1) ? TBM : 2;

    __shared__ _Float16 sA[4][TBM][BK];
    __shared__ _Float16 sB[4][TBF][BK];
    __shared__ int sIdx[NI][9];

    const int t  = threadIdx.x;
    const int b  = blockIdx.z;
    const int m0 = blockIdx.y * TBM;
    const int f0 = blockIdx.x * TBF;
    const int lane = t & 63;
    const int wid  = t >> 6;
    const int wm = wid / WF;
    const int wf = wid % WF;
    const int lm = lane & 15;
    const int lg = lane >> 4;
    const int Fi = 1 << FiLog;

    f32x4 acc[FM][FF];
    #pragma unroll
    for (int i = 0; i < FM; ++i)
        #pragma unroll
        for (int j = 0; j < FF; ++j)
            acc[i][j] = (f32x4)0.0f;

    if constexpr (AMODE == 1) {
        for (int i = t; i < TBM * 9; i += 256) {
            int r = i / 9, k = i - r * 9;
            int rc = m0 + r; if (rc >= M) rc = M - 1;
            sIdx[r][k] = idx[rc * 9 + k];
        }
        __syncthreads();
    } else if constexpr (AMODE == 5) {
        if (t < 18) {
            int r = t / 9, k = t - r * 9;
            sIdx[r][k] = idx[((m0 >> 6) + r) * 9 + k];
        }
        __syncthreads();
    }

    auto stage = [&](int buf, int ks) {
        if constexpr (AMODE != 2) {
            #pragma unroll
            for (int j = 0; j < LPS_A; ++j) {
                int c   = t + j * 256;
                int row = c >> 2;
                int sw  = ((c & 3) ^ ((row >> 1) & 3)) * 8;   // pre-swizzled source chunk
                int col = ks * BK + sw;
                const _Float16* src;
                if constexpr (AMODE == 3) {
                    int rc = m0 + row; if (rc >= M) rc = M - 1;
                    src = Aw + (u64)rc * Np + col;
                } else if constexpr (AMODE == 1) {
                    int k = col >> FiLog, fi = col & (Fi - 1);
                    src = Aw + (u64)sIdx[row][k] * a_rs + b * Fi + fi;
                } else if constexpr (AMODE == 4) {
                    int k = col >> FiLog, fi = col & (Fi - 1);
                    src = Aw + (u64)k * a_rs + (m0 + row) * Fi + fi;
                } else {  // 5
                    int k = col >> FiLog, fi = col & (Fi - 1);
                    int bb = (m0 + row) & 63;
                    src = Aw + (u64)sIdx[row >> 6][k] * a_rs + bb * Fi + fi;
                }
                gl16(src, &sA[buf][row][(c & 3) * 8]);   // linear dest
            }
        }
        if constexpr (!BSM) {
            #pragma unroll
            for (int j = 0; j < LPS_B; ++j) {
                int c   = t + j * 256;
                int row = c >> 2;
                int sw  = ((c & 3) ^ ((row >> 1) & 3)) * 8;
                gl16(Bw + (u64)(f0 + row) * Np + ks * BK + sw, &sB[buf][row][(c & 3) * 8]);
            }
        } else {
            if (wid == 0) {
                int c   = t;
                int row = c >> 2;
                int sw  = ((c & 3) ^ ((row >> 1) & 3)) * 8;
                gl16(Bw + (u64)(f0 + row) * Np + ks * BK + sw, &sB[buf][row][(c & 3) * 8]);
            }
        }
    };

    auto compute = [&](int buf) {
        const int sa = (lg ^ ((lm >> 1) & 3)) * 8;   // un-swizzle on read
        half8 af[FM], bf[FF];
        #pragma unroll
        for (int i = 0; i < FM; ++i)
            af[i] = *(const half8*)&sA[buf][wm * (FM * 16) + i * 16 + lm][sa];
        #pragma unroll
        for (int j = 0; j < FF; ++j)
            bf[j] = *(const half8*)&sB[buf][wf * (FF * 16) + j * 16 + lm][sa];
        #pragma unroll
        for (int i = 0; i < FM; ++i)
            #pragma unroll
            for (int j = 0; j < FF; ++j)
                acc[i][j] = __builtin_amdgcn_mfma_f32_16x16x32_f16(af[i], bf[j], acc[i][j], 0, 0, 0);
    };

    if constexpr (AMODE == 2) {
        stage(0, 0);   // B only
        {
            int row = t >> 1;
            int base = (t & 1) * 16;
            int rg = m0 + row;
            #pragma unroll
            for (int q = 0; q < 16; ++q) {
                int n = base + q;
                _Float16 val = (_Float16)0.f;
                if (rg < M && n < 27) {
                    int k = n / 3, fi = n - k * 3;
                    val = Aw[(u64)idx[rg * 9 + k] * a_rs + b * 3 + fi];
                }
                int ch = (n >> 3) ^ ((row >> 1) & 3);
                sA[0][row][ch * 8 + (n & 7)] = val;   // store swizzled
            }
        }
        __syncthreads();
        compute(0);
    } else {
        int kb = 0, ke = Np / BK;
        if constexpr (AMODE == 4) { kb = b * ksp; ke = kb + ksp; }
        stage(0, kb);
        if (kb + 1 < ke) stage(1, kb + 1);
        if (kb + 2 < ke) stage(2, kb + 2);
        for (int ks = kb; ks < ke; ++ks) {
            int rem = ke - ks;
            if (rem >= 3) {
                if constexpr (LW0 == LWX) vwait<2 * LW0>();
                else { if (wid == 0) vwait<2 * LW0>(); else vwait<2 * LWX>(); }
            } else if (rem == 2) {
                if constexpr (LW0 == LWX) vwait<LW0>();
                else { if (wid == 0) vwait<LW0>(); else vwait<LWX>(); }
            } else {
                vwait<0>();
            }
            barx();                                  // single barrier per step
            if (ks + 3 < ke) stage((ks - kb + 3) & 3, ks + 3);
            compute((ks - kb) & 3);
        }
    }

    #pragma unroll
    for (int j = 0; j < FF; ++j) {
        int fl = f0 + wf * (FF * 16) + j * 16 + lm;
        float bv = 0.f;
        if (bias != nullptr && fl < F) bv = bias[fl];
        #pragma unroll
        for (int i = 0; i < FM; ++i) {
            #pragma unroll
            for (int r = 0; r < 4; ++r) {
                int m = m0 + wm * (FM * 16) + i * 16 + lg * 4 + r;
                float v = acc[i][j][r] + bv;
                if (flags & 1) v = (v > 0.f) ? v : expm1f(v);
                if constexpr (EPI == EPI_NAT) {
                    if (m < M && fl < F)
                        ((_Float16*)Cp)[(u64)m * c_rs + fl] = (_Float16)v;
                } else if constexpr (EPI == EPI_TR) {
                    if (m < Mp_out && fl < F) {
                        float o = (m < M && !((flags & 2) && m == M - 1)) ? v : 0.f;
                        ((_Float16*)Cp)[(u64)b * c_rs + (u64)fl * Mp_out + m] = (_Float16)o;
                    }
                } else if constexpr (EPI == EPI_FCD) {
                    if (m < M && fl < F)
                        ((_Float16*)Cp)[((u64)m * 256 + (fl & 255)) * 32 + (fl >> 8)] = (_Float16)v;
                } else if constexpr (EPI == EPI_PART) {
                    if (m < M && fl < F)
                        ((float*)Cp)[(u64)b * c_rs + (u64)m * F + fl] = v;
                } else {  // EPI_OUT (rows folded: m = v*64+b)
                    if (m < M && fl < F) {
                        int vo = m >> 6, bb = m & 63;
                        float o = ((flags & 2) && vo == Mp_out - 1) ? 0.f : v;
                        ((float*)Cp)[((u64)bb * Mp_out + vo) * 3 + fl] = o;
                    }
                }
            }
        }
    }
}

// ---- fused weight conversion ----
struct CvtPtrs { const float* p[18]; };

constexpr int CV_R[18]  = {1257,5024,315,1257,80,315,21,80,  64,64,128,256,256,5376,128,64,64,16};
constexpr int CV_N[18]  = {5024,1257,1257,315,315,80,80,21,  27,576,576,1152,5376,256,2304,1152,576,576};
constexpr int CV_NP[18] = {5120,1280,1280,320,320,96,96,32,  32,576,576,1152,5376,256,2304,1152,576,576};
constexpr int CV_F[18]  = {0,0,0,0,0,0,0,0,  64,64,128,256,256,5376,128,64,64,3};

constexpr u64 cv_elems(int i) { return (u64)CV_R[i] * CV_NP[i]; }
constexpr u64 cv_off(int i) { u64 o = 0; for (int j = 0; j < i; ++j) o += (cv_elems(j) + 255) & ~(u64)255; return o; }
constexpr int cv_blk(int i) { return (int)((cv_elems(i) + 255) >> 8); }
constexpr int cv_start(int i) { int s = 0; for (int j = 0; j < i; ++j) s += cv_blk(j); return s; }

__global__ __launch_bounds__(256) void cvt_all(CvtPtrs ps, _Float16* __restrict__ dst)
{
    const int bx = blockIdx.x, t = threadIdx.x;
    #pragma unroll
    for (int i = 0; i < 18; ++i) {
        if (bx >= cv_start(i) && bx < cv_start(i + 1)) {
            const u64 e = (u64)(bx - cv_start(i)) * 256 + t;
            if (e < cv_elems(i)) {
                const int NP = CV_NP[i], N = CV_N[i], Fo = CV_F[i];
                int row = (int)(e / (u64)NP);
                int col = (int)(e - (u64)row * NP);
                float v = 0.f;
                const float* s = ps.p[i];
                if (Fo == 0) { if (col < N) v = s[(u64)row * N + col]; }
                else         { if (col < N && row < Fo) v = s[(u64)col * Fo + row]; }
                dst[cv_off(i) + e] = (_Float16)v;
            }
        }
    }
}

__global__ void cvt_x(const float* __restrict__ src, _Float16* __restrict__ dst)
{
    int i = blockIdx.x * 256 + threadIdx.x;
    if (i >= 64 * 5024 * 3) return;
    int v = i / 192;
    int r = i - v * 192;
    int b = r / 3, c = r - b * 3;
    dst[i] = (_Float16)src[((u64)b * 5024 + v) * 3 + c];
}

__global__ void reduce_fce(const float* __restrict__ part, const float* __restrict__ bias,
                           _Float16* __restrict__ z)
{
    int i = blockIdx.x * 256 + threadIdx.x;  // 64*256
    int fl = i & 255;
    float s = bias[fl];
    #pragma unroll
    for (int p = 0; p < 8; ++p) s += part[(u64)p * 16384 + i];
    z[i] = (_Float16)s;
}

extern "C" void kernel_launch(void* const* d_in, const int* in_sizes, int n_in,
                              void* d_out, int out_size, void* d_ws, size_t ws_size,
                              hipStream_t stream)
{
    const float* x  = (const float*)d_in[0];
    const int* s0 = (const int*)d_in[1];
    const int* s1 = (const int*)d_in[2];
    const int* s2 = (const int*)d_in[3];
    const int* s3 = (const int*)d_in[4];
    const float* be0 = (const float*)d_in[14];
    const float* be1 = (const float*)d_in[16];
    const float* be2 = (const float*)d_in[18];
    const float* be3 = (const float*)d_in[20];
    const float* fceb = (const float*)d_in[22];
    const float* fcdb = (const float*)d_in[24];
    const float* bd0 = (const float*)d_in[26];
    const float* bd1 = (const float*)d_in[28];
    const float* bd2 = (const float*)d_in[30];
    const float* bd3 = (const float*)d_in[32];

    _Float16* W = (_Float16*)d_ws;
    size_t off = 0;
    auto alloc = [&](size_t e) { size_t o = off; off += (e + 255) & ~(size_t)255; return o; };

    const size_t oActV = alloc((size_t)5024 * 4096);   // [vertex][(b,f)]
    const size_t oActT = alloc((size_t)4096 * 5120);   // [(b,f)][vertex_padded]
    const size_t oZ    = alloc((size_t)64 * 256);
    const size_t oPart = alloc((size_t)8 * 64 * 256 * 2);   // fp32 partials (fce)
    const size_t oU3in = alloc((size_t)16384 * 32);
    const size_t oXp   = alloc((size_t)5024 * 192);
    const size_t oCvt  = alloc((size_t)(cv_off(17) + ((cv_elems(17) + 255) & ~(u64)255)));
    auto wofs = [&](int i) { return oCvt + (size_t)cv_off(i); };

    // ---- conversions ----
    cvt_x<<<dim3((64 * 5024 * 3 + 255) / 256), 256, 0, stream>>>(x, W + oXp);
    {
        CvtPtrs ps;
        ps.p[0] = (const float*)d_in[5];   // D0
        ps.p[1] = (const float*)d_in[6];   // U0
        ps.p[2] = (const float*)d_in[7];   // D1
        ps.p[3] = (const float*)d_in[8];   // U1
        ps.p[4] = (const float*)d_in[9];   // D2
        ps.p[5] = (const float*)d_in[10];  // U2
        ps.p[6] = (const float*)d_in[11];  // D3
        ps.p[7] = (const float*)d_in[12];  // U3
        ps.p[8] = (const float*)d_in[13];  // We0
        ps.p[9] = (const float*)d_in[15];  // We1
        ps.p[10] = (const float*)d_in[17]; // We2
        ps.p[11] = (const float*)d_in[19]; // We3
        ps.p[12] = (const float*)d_in[21]; // fceW
        ps.p[13] = (const float*)d_in[23]; // fcdW
        ps.p[14] = (const float*)d_in[25]; // Wd0
        ps.p[15] = (const float*)d_in[27]; // Wd1
        ps.p[16] = (const float*)d_in[29]; // Wd2
        ps.p[17] = (const float*)d_in[31]; // Wd3
        cvt_all<<<dim3(cv_start(18)), 256, 0, stream>>>(ps, W + oCvt);
    }
    hipMemsetAsync(W + oU3in, 0, (size_t)16384 * 32 * sizeof(_Float16), stream);

    #define GEMM(AM, EP, BM_, BF_, WM_, WF_, gx, gy, gz, Aw_, ars_, idx_, FiL_, Bw_, bias_, Cp_, crs_, Mp_, M_, Np_, F_, fl_, ksp_) \
        gemm_k<AM, EP, BM_, BF_, WM_, WF_><<<dim3(gx, gy, gz), 256, 0, stream>>>( \
            Aw_, ars_, idx_, FiL_, Bw_, bias_, Cp_, crs_, Mp_, M_, Np_, F_, fl_, ksp_)
    #define POOL(TBM_, OCC_, gx, gy, Aw_, Bw_, Cp_, M_, Np_, crs_) \
        pool2_k<TBM_, OCC_><<<dim3(gx, gy), 256, 0, stream>>>(Aw_, Bw_, Cp_, M_, Np_, crs_)

    // ---- encoder ----
    GEMM(2, EPI_TR, 128, 64, 2, 2, 1, 40, 64, W + oXp, 192, s0, 0,
         W + wofs(8), be0, W + oActT, (u64)64 * 5120, 5120, 5024, 32, 64, 3, 0);
    POOL(64, 3, 32, 20, W + wofs(0), W + oActT, W + oActV, 1257, 5120, 4096);
    GEMM(1, EPI_TR, 128, 64, 2, 2, 1, 10, 64, W + oActV, 4096, s1, 6,
         W + wofs(9), be1, W + oActT, (u64)64 * 1280, 1280, 1257, 576, 64, 3, 0);
    POOL(64, 3, 32, 5, W + wofs(2), W + oActT, W + oActV, 315, 1280, 4096);
    GEMM(1, EPI_TR, 128, 64, 2, 2, 2, 3, 64, W + oActV, 4096, s2, 6,
         W + wofs(10), be2, W + oActT, (u64)128 * 320, 320, 315, 576, 128, 3, 0);
    POOL(64, 3, 64, 2, W + wofs(4), W + oActT, W + oActV, 80, 320, 8192);
    GEMM(1, EPI_TR, 128, 64, 2, 2, 4, 1, 64, W + oActV, 8192, s3, 7,
         W + wofs(11), be3, W + oActT, (u64)256 * 96, 96, 80, 1152, 256, 3, 0);
    POOL(64, 3, 128, 1, W + wofs(6), W + oActT, W + oActV, 21, 96, 16384);
    // ---- bottleneck ----
    GEMM(4, EPI_PART, 64, 64, 2, 2, 4, 1, 8, W + oActV, 16384, nullptr, 8,
         W + wofs(12), nullptr, W + oPart, (u64)64 * 256, 0, 64, 5376, 256, 0, 21);
    reduce_fce<<<dim3(64), 256, 0, stream>>>((const float*)(W + oPart), fceb, W + oZ);
    GEMM(3, EPI_FCD, 64, 128, 2, 2, 42, 1, 1, W + oZ, 0, nullptr, 0,
         W + wofs(13), fcdb, W + oU3in, 0, 0, 64, 256, 5376, 0, 0);
    // ---- decoder ----
    POOL(64, 3, 128, 2, W + wofs(7), W + oU3in, W + oActV, 80, 32, 16384);
    GEMM(1, EPI_TR, 128, 64, 2, 2, 2, 1, 64, W + oActV, 16384, s3, 8,
         W + wofs(14), bd0, W + oActT, (u64)128 * 96, 96, 80, 2304, 128, 3, 0);
    POOL(64, 3, 64, 5, W + wofs(5), W + oActT, W + oActV, 315, 96, 8192);
    GEMM(1, EPI_TR, 128, 64, 2, 2, 1, 3, 64, W + oActV, 8192, s2, 7,
         W + wofs(15), bd1, W + oActT, (u64)64 * 320, 320, 315, 1152, 64, 3, 0);
    POOL(64, 3, 32, 20, W + wofs(3), W + oActT, W + oActV, 1257, 320, 4096);
    GEMM(1, EPI_TR, 128, 64, 2, 2, 1, 10, 64, W + oActV, 4096, s1, 6,
         W + wofs(16), bd2, W + oActT, (u64)64 * 1280, 1280, 1257, 576, 64, 3, 0);
    POOL(64, 3, 32, 79, W + wofs(1), W + oActT, W + oActV, 5024, 1280, 4096);
    GEMM(5, EPI_OUT, 128, 16, 4, 1, 1, 2512, 1, W + oActV, 4096, s0, 6,
         W + wofs(17), bd3, d_out, 0, 5024, 321536, 576, 3, 2, 0);
    #undef GEMM
    #undef POOL
}

// Round 14
// 604.135 us; speedup vs baseline: 1.2887x; 1.0168x over previous
//
#include <hip/hip_runtime.h>
#include <math.h>

typedef __attribute__((ext_vector_type(8))) _Float16 half8;
typedef __attribute__((ext_vector_type(4))) float f32x4;
typedef unsigned long long u64;

#define BK 32

#define EPI_NAT  0
#define EPI_TR   1
#define EPI_FCD  2
#define EPI_OUT  3
#define EPI_PART 4

typedef const __attribute__((address_space(1))) void* gas1;
typedef __attribute__((address_space(3))) void* las3;

__device__ __forceinline__ void gl16(const void* g, void* l) {
    __builtin_amdgcn_global_load_lds((gas1)g, (las3)l, 16, 0, 0);
}
template<int N> __device__ __forceinline__ void vwait() {
    asm volatile("s_waitcnt vmcnt(%0)" :: "n"(N) : "memory");
}
__device__ __forceinline__ void barx() {
    asm volatile("" ::: "memory");
    __builtin_amdgcn_s_barrier();
    asm volatile("" ::: "memory");
}

// ============ pool kernel (r9 proven): 256 thr, 4 waves (2x2), TBMx128, 3-buf ============
template<int TBM, int OCC>
__global__ __launch_bounds__(256, OCC) void pool2_k(
    const _Float16* __restrict__ Aw, const _Float16* __restrict__ Bw,
    _Float16* __restrict__ Cp, int M, int Np, u64 c_rs)
{
    constexpr int FM  = TBM / 32;          // wave m-frags (WM=2)
    constexpr int LPS = TBM / 64 + 2;      // gl16 per thread per stage

    __shared__ _Float16 sA[3][TBM][BK];
    __shared__ _Float16 sB[3][128][BK];

    const int t  = threadIdx.x;
    const int m0 = blockIdx.y * TBM;
    const int f0 = blockIdx.x * 128;
    const int lane = t & 63;
    const int wid  = t >> 6;
    const int wm = wid >> 1;
    const int wf = wid & 1;
    const int lm = lane & 15;
    const int lg = lane >> 4;

    f32x4 acc[FM][4];
    #pragma unroll
    for (int i = 0; i < FM; ++i)
        #pragma unroll
        for (int j = 0; j < 4; ++j)
            acc[i][j] = (f32x4)0.0f;

    auto stage = [&](int buf, int ks) {
        #pragma unroll
        for (int j = 0; j < TBM / 64; ++j) {
            int c   = t + j * 256;
            int row = c >> 2;
            int sw  = ((c & 3) ^ ((row >> 1) & 3)) * 8;   // pre-swizzled source chunk
            int rc  = m0 + row; if (rc >= M) rc = M - 1;
            gl16(Aw + (u64)rc * Np + ks * BK + sw,
                 (_Float16*)&sA[buf][0][0] + (u64)c * 8);  // linear dest
        }
        #pragma unroll
        for (int j = 0; j < 2; ++j) {
            int c   = t + j * 256;
            int row = c >> 2;
            int sw  = ((c & 3) ^ ((row >> 1) & 3)) * 8;
            gl16(Bw + (u64)(f0 + row) * Np + ks * BK + sw,
                 (_Float16*)&sB[buf][0][0] + (u64)c * 8);
        }
    };

    auto compute = [&](int buf) {
        const int sa = (lg ^ ((lm >> 1) & 3)) * 8;        // un-swizzle on read
        half8 af[FM], bf[4];
        #pragma unroll
        for (int i = 0; i < FM; ++i)
            af[i] = *(const half8*)&sA[buf][wm * (FM * 16) + i * 16 + lm][sa];
        #pragma unroll
        for (int j = 0; j < 4; ++j)
            bf[j] = *(const half8*)&sB[buf][wf * 64 + j * 16 + lm][sa];
        #pragma unroll
        for (int i = 0; i < FM; ++i)
            #pragma unroll
            for (int j = 0; j < 4; ++j)
                acc[i][j] = __builtin_amdgcn_mfma_f32_16x16x32_f16(af[i], bf[j], acc[i][j], 0, 0, 0);
    };

    const int ke = Np / BK;
    stage(0, 0);
    if (1 < ke) stage(1, 1);
    if (2 < ke) stage(2, 2);
    int cur = 0;
    for (int ks = 0; ks < ke; ++ks) {
        int rem = ke - ks;
        if (rem >= 3)      vwait<2 * LPS>();
        else if (rem == 2) vwait<LPS>();
        else               vwait<0>();
        barx();
        compute(cur);
        barx();
        if (ks + 3 < ke) stage(cur, ks + 3);
        cur = (cur == 2) ? 0 : cur + 1;
    }

    #pragma unroll
    for (int j = 0; j < 4; ++j) {
        int fl = f0 + wf * 64 + j * 16 + lm;
        #pragma unroll
        for (int i = 0; i < FM; ++i) {
            #pragma unroll
            for (int r = 0; r < 4; ++r) {
                int m = m0 + wm * (FM * 16) + i * 16 + lg * 4 + r;
                if (m < M)
                    Cp[(u64)m * c_rs + fl] = (_Float16)acc[i][j][r];
            }
        }
    }
}

// ============ pool2b: 128 thr, 2 waves (1x2), 64x128 tile, wave 64x64 ============
// ratio FM*FF/(FM+FF)=2.0 AND 4 blocks/CU (36KB LDS) — both port-efficiency and occupancy.
// Same 3-buf / 2-barrier / counted-vmcnt pipeline as pool2_k (proven in r9).
__global__ __launch_bounds__(128, 2) void pool2b_k(
    const _Float16* __restrict__ Aw, const _Float16* __restrict__ Bw,
    _Float16* __restrict__ Cp, int M, int Np, u64 c_rs)
{
    constexpr int LPS = 6;   // 2 A-chunks + 4 B-chunks per thread per stage

    __shared__ _Float16 sA[3][64][BK];
    __shared__ _Float16 sB[3][128][BK];

    const int t  = threadIdx.x;
    const int m0 = blockIdx.y * 64;
    const int f0 = blockIdx.x * 128;
    const int lane = t & 63;
    const int wf  = t >> 6;       // 0..1
    const int lm = lane & 15;
    const int lg = lane >> 4;

    f32x4 acc[4][4];
    #pragma unroll
    for (int i = 0; i < 4; ++i)
        #pragma unroll
        for (int j = 0; j < 4; ++j)
            acc[i][j] = (f32x4)0.0f;

    auto stage = [&](int buf, int ks) {
        #pragma unroll
        for (int j = 0; j < 2; ++j) {      // A: 64x32 = 256 chunks
            int c   = t + j * 128;
            int row = c >> 2;
            int sw  = ((c & 3) ^ ((row >> 1) & 3)) * 8;
            int rc  = m0 + row; if (rc >= M) rc = M - 1;
            gl16(Aw + (u64)rc * Np + ks * BK + sw,
                 (_Float16*)&sA[buf][0][0] + (u64)c * 8);
        }
        #pragma unroll
        for (int j = 0; j < 4; ++j) {      // B: 128x32 = 512 chunks
            int c   = t + j * 128;
            int row = c >> 2;
            int sw  = ((c & 3) ^ ((row >> 1) & 3)) * 8;
            gl16(Bw + (u64)(f0 + row) * Np + ks * BK + sw,
                 (_Float16*)&sB[buf][0][0] + (u64)c * 8);
        }
    };

    auto compute = [&](int buf) {
        const int sa = (lg ^ ((lm >> 1) & 3)) * 8;
        half8 af[4], bf[4];
        #pragma unroll
        for (int i = 0; i < 4; ++i)
            af[i] = *(const half8*)&sA[buf][i * 16 + lm][sa];
        #pragma unroll
        for (int j = 0; j < 4; ++j)
            bf[j] = *(const half8*)&sB[buf][wf * 64 + j * 16 + lm][sa];
        #pragma unroll
        for (int i = 0; i < 4; ++i)
            #pragma unroll
            for (int j = 0; j < 4; ++j)
                acc[i][j] = __builtin_amdgcn_mfma_f32_16x16x32_f16(af[i], bf[j], acc[i][j], 0, 0, 0);
    };

    const int ke = Np / BK;
    stage(0, 0);
    if (1 < ke) stage(1, 1);
    if (2 < ke) stage(2, 2);
    int cur = 0;
    for (int ks = 0; ks < ke; ++ks) {
        int rem = ke - ks;
        if (rem >= 3)      vwait<2 * LPS>();
        else if (rem == 2) vwait<LPS>();
        else               vwait<0>();
        barx();
        compute(cur);
        barx();
        if (ks + 3 < ke) stage(cur, ks + 3);
        cur = (cur == 2) ? 0 : cur + 1;
    }

    #pragma unroll
    for (int j = 0; j < 4; ++j) {
        int fl = f0 + wf * 64 + j * 16 + lm;
        #pragma unroll
        for (int i = 0; i < 4; ++i) {
            #pragma unroll
            for (int r = 0; r < 4; ++r) {
                int m = m0 + i * 16 + lg * 4 + r;
                if (m < M)
                    Cp[(u64)m * c_rs + fl] = (_Float16)acc[i][j][r];
            }
        }
    }
}

// ============ general kernel (sconv / fc) — r9 proven ============
// AMODE: 1 sconv gather (idx via LDS), 2 sconv0 (Fi=3, nk=1),
//        3 fc, 4 fc-enc split-K, 5 sconv rows-folded [Wd3]
template<int AMODE, int EPI, int TBM, int TBF, int WM, int WF>
__global__ __launch_bounds__(256) void gemm_k(
    const _Float16* __restrict__ Aw, u64 a_rs,
    const int* __restrict__ idx, int FiLog,
    const _Float16* __restrict__ Bw,
    const float* __restrict__ bias,
    void* __restrict__ Cp, u64 c_rs, int Mp_out,
    int M, int Np, int F, int flags, int ksp)   // flags: bit0 ELU, bit1 zeroLast
{
    constexpr int FM = TBM / WM / 16;
    constexpr int FF = TBF / WF / 16;
    constexpr int LPS_A = TBM / 64;
    constexpr bool BSM = (TBF < 64);
    constexpr int LPS_B = BSM ? 0 : TBF / 64;
    constexpr int LW0 = LPS_A + (BSM ? 1 : LPS_B);
    constexpr int LWX = LPS_A + LPS_B;
    constexpr int NI = (AMODE == 1) ? TBM : 2;

    __shared__ _Float16 sA[3][TBM][BK];
    __shared__ _Float16 sB[3][TBF][BK];
    __shared__ int sIdx[NI][9];

    const int t  = threadIdx.x;
    const int b  = blockIdx.z;
    const int m0 = blockIdx.y * TBM;
    const int f0 = blockIdx.x * TBF;
    const int lane = t & 63;
    const int wid  = t >> 6;
    const int wm = wid / WF;
    const int wf = wid % WF;
    const int lm = lane & 15;
    const int lg = lane >> 4;
    const int Fi = 1 << FiLog;

    f32x4 acc[FM][FF];
    #pragma unroll
    for (int i = 0; i < FM; ++i)
        #pragma unroll
        for (int j = 0; j < FF; ++j)
            acc[i][j] = (f32x4)0.0f;

    if constexpr (AMODE == 1) {
        for (int i = t; i < TBM * 9; i += 256) {
            int r = i / 9, k = i - r * 9;
            int rc = m0 + r; if (rc >= M) rc = M - 1;
            sIdx[r][k] = idx[rc * 9 + k];
        }
        __syncthreads();
    } else if constexpr (AMODE == 5) {
        if (t < 18) {
            int r = t / 9, k = t - r * 9;
            sIdx[r][k] = idx[((m0 >> 6) + r) * 9 + k];
        }
        __syncthreads();
    }

    auto stage = [&](int buf, int ks) {
        if constexpr (AMODE != 2) {
            #pragma unroll
            for (int j = 0; j < LPS_A; ++j) {
                int c   = t + j * 256;
                int row = c >> 2;
                int sw  = ((c & 3) ^ ((row >> 1) & 3)) * 8;   // pre-swizzled source chunk
                int col = ks * BK + sw;
                const _Float16* src;
                if constexpr (AMODE == 3) {
                    int rc = m0 + row; if (rc >= M) rc = M - 1;
                    src = Aw + (u64)rc * Np + col;
                } else if constexpr (AMODE == 1) {
                    int k = col >> FiLog, fi = col & (Fi - 1);
                    src = Aw + (u64)sIdx[row][k] * a_rs + b * Fi + fi;
                } else if constexpr (AMODE == 4) {
                    int k = col >> FiLog, fi = col & (Fi - 1);
                    src = Aw + (u64)k * a_rs + (m0 + row) * Fi + fi;
                } else {  // 5
                    int k = col >> FiLog, fi = col & (Fi - 1);
                    int bb = (m0 + row) & 63;
                    src = Aw + (u64)sIdx[row >> 6][k] * a_rs + bb * Fi + fi;
                }
                gl16(src, &sA[buf][row][(c & 3) * 8]);   // linear dest
            }
        }
        if constexpr (!BSM) {
            #pragma unroll
            for (int j = 0; j < LPS_B; ++j) {
                int c   = t + j * 256;
                int row = c >> 2;
                int sw  = ((c & 3) ^ ((row >> 1) & 3)) * 8;
                gl16(Bw + (u64)(f0 + row) * Np + ks * BK + sw, &sB[buf][row][(c & 3) * 8]);
            }
        } else {
            if (wid == 0) {
                int c   = t;
                int row = c >> 2;
                int sw  = ((c & 3) ^ ((row >> 1) & 3)) * 8;
                gl16(Bw + (u64)(f0 + row) * Np + ks * BK + sw, &sB[buf][row][(c & 3) * 8]);
            }
        }
    };

    auto compute = [&](int buf) {
        const int sa = (lg ^ ((lm >> 1) & 3)) * 8;   // un-swizzle on read
        half8 af[FM], bf[FF];
        #pragma unroll
        for (int i = 0; i < FM; ++i)
            af[i] = *(const half8*)&sA[buf][wm * (FM * 16) + i * 16 + lm][sa];
        #pragma unroll
        for (int j = 0; j < FF; ++j)
            bf[j] = *(const half8*)&sB[buf][wf * (FF * 16) + j * 16 + lm][sa];
        #pragma unroll
        for (int i = 0; i < FM; ++i)
            #pragma unroll
            for (int j = 0; j < FF; ++j)
                acc[i][j] = __builtin_amdgcn_mfma_f32_16x16x32_f16(af[i], bf[j], acc[i][j], 0, 0, 0);
    };

    if constexpr (AMODE == 2) {
        stage(0, 0);   // B only
        {
            int row = t >> 1;
            int base = (t & 1) * 16;
            int rg = m0 + row;
            #pragma unroll
            for (int q = 0; q < 16; ++q) {
                int n = base + q;
                _Float16 val = (_Float16)0.f;
                if (rg < M && n < 27) {
                    int k = n / 3, fi = n - k * 3;
                    val = Aw[(u64)idx[rg * 9 + k] * a_rs + b * 3 + fi];
                }
                int ch = (n >> 3) ^ ((row >> 1) & 3);
                sA[0][row][ch * 8 + (n & 7)] = val;   // store swizzled
            }
        }
        __syncthreads();
        compute(0);
    } else {
        int kb = 0, ke = Np / BK;
        if constexpr (AMODE == 4) { kb = b * ksp; ke = kb + ksp; }
        stage(0, kb);
        if (kb + 1 < ke) stage(1, kb + 1);
        if (kb + 2 < ke) stage(2, kb + 2);
        int cur = 0;
        for (int ks = kb; ks < ke; ++ks) {
            int rem = ke - ks;
            if (rem >= 3) {
                if constexpr (LW0 == LWX) vwait<2 * LW0>();
                else { if (wid == 0) vwait<2 * LW0>(); else vwait<2 * LWX>(); }
            } else if (rem == 2) {
                if constexpr (LW0 == LWX) vwait<LW0>();
                else { if (wid == 0) vwait<LW0>(); else vwait<LWX>(); }
            } else {
                vwait<0>();
            }
            barx();
            compute(cur);
            barx();
            if (ks + 3 < ke) stage(cur, ks + 3);
            cur = (cur == 2) ? 0 : cur + 1;
        }
    }

    #pragma unroll
    for (int j = 0; j < FF; ++j) {
        int fl = f0 + wf * (FF * 16) + j * 16 + lm;
        float bv = 0.f;
        if (bias != nullptr && fl < F) bv = bias[fl];
        #pragma unroll
        for (int i = 0; i < FM; ++i) {
            #pragma unroll
            for (int r = 0; r < 4; ++r) {
                int m = m0 + wm * (FM * 16) + i * 16 + lg * 4 + r;
                float v = acc[i][j][r] + bv;
                if (flags & 1) v = (v > 0.f) ? v : expm1f(v);
                if constexpr (EPI == EPI_NAT) {
                    if (m < M && fl < F)
                        ((_Float16*)Cp)[(u64)m * c_rs + fl] = (_Float16)v;
                } else if constexpr (EPI == EPI_TR) {
                    if (m < Mp_out && fl < F) {
                        float o = (m < M && !((flags & 2) && m == M - 1)) ? v : 0.f;
                        ((_Float16*)Cp)[(u64)b * c_rs + (u64)fl * Mp_out + m] = (_Float16)o;
                    }
                } else if constexpr (EPI == EPI_FCD) {
                    if (m < M && fl < F)
                        ((_Float16*)Cp)[((u64)m * 256 + (fl & 255)) * 32 + (fl >> 8)] = (_Float16)v;
                } else if constexpr (EPI == EPI_PART) {
                    if (m < M && fl < F)
                        ((float*)Cp)[(u64)b * c_rs + (u64)m * F + fl] = v;
                } else {  // EPI_OUT (rows folded: m = v*64+b)
                    if (m < M && fl < F) {
                        int vo = m >> 6, bb = m & 63;
                        float o = ((flags & 2) && vo == Mp_out - 1) ? 0.f : v;
                        ((float*)Cp)[((u64)bb * Mp_out + vo) * 3 + fl] = o;
                    }
                }
            }
        }
    }
}

// ---- fused weight conversion ----
struct CvtPtrs { const float* p[18]; };

constexpr int CV_R[18]  = {1257,5024,315,1257,80,315,21,80,  64,64,128,256,256,5376,128,64,64,16};
constexpr int CV_N[18]  = {5024,1257,1257,315,315,80,80,21,  27,576,576,1152,5376,256,2304,1152,576,576};
constexpr int CV_NP[18] = {5120,1280,1280,320,320,96,96,32,  32,576,576,1152,5376,256,2304,1152,576,576};
constexpr int CV_F[18]  = {0,0,0,0,0,0,0,0,  64,64,128,256,256,5376,128,64,64,3};

constexpr u64 cv_elems(int i) { return (u64)CV_R[i] * CV_NP[i]; }
constexpr u64 cv_off(int i) { u64 o = 0; for (int j = 0; j < i; ++j) o += (cv_elems(j) + 255) & ~(u64)255; return o; }
constexpr int cv_blk(int i) { return (int)((cv_elems(i) + 255) >> 8); }
constexpr int cv_start(int i) { int s = 0; for (int j = 0; j < i; ++j) s += cv_blk(j); return s; }

__global__ __launch_bounds__(256) void cvt_all(CvtPtrs ps, _Float16* __restrict__ dst)
{
    const int bx = blockIdx.x, t = threadIdx.x;
    #pragma unroll
    for (int i = 0; i < 18; ++i) {
        if (bx >= cv_start(i) && bx < cv_start(i + 1)) {
            const u64 e = (u64)(bx - cv_start(i)) * 256 + t;
            if (e < cv_elems(i)) {
                const int NP = CV_NP[i], N = CV_N[i], Fo = CV_F[i];
                int row = (int)(e / (u64)NP);
                int col = (int)(e - (u64)row * NP);
                float v = 0.f;
                const float* s = ps.p[i];
                if (Fo == 0) { if (col < N) v = s[(u64)row * N + col]; }
                else         { if (col < N && row < Fo) v = s[(u64)col * Fo + row]; }
                dst[cv_off(i) + e] = (_Float16)v;
            }
        }
    }
}

__global__ void cvt_x(const float* __restrict__ src, _Float16* __restrict__ dst)
{
    int i = blockIdx.x * 256 + threadIdx.x;
    if (i >= 64 * 5024 * 3) return;
    int v = i / 192;
    int r = i - v * 192;
    int b = r / 3, c = r - b * 3;
    dst[i] = (_Float16)src[((u64)b * 5024 + v) * 3 + c];
}

__global__ void reduce_fce(const float* __restrict__ part, const float* __restrict__ bias,
                           _Float16* __restrict__ z)
{
    int i = blockIdx.x * 256 + threadIdx.x;  // 64*256
    int fl = i & 255;
    float s = bias[fl];
    #pragma unroll
    for (int p = 0; p < 8; ++p) s += part[(u64)p * 16384 + i];
    z[i] = (_Float16)s;
}

extern "C" void kernel_launch(void* const* d_in, const int* in_sizes, int n_in,
                              void* d_out, int out_size, void* d_ws, size_t ws_size,
                              hipStream_t stream)
{
    const float* x  = (const float*)d_in[0];
    const int* s0 = (const int*)d_in[1];
    const int* s1 = (const int*)d_in[2];
    const int* s2 = (const int*)d_in[3];
    const int* s3 = (const int*)d_in[4];
    const float* be0 = (const float*)d_in[14];
    const float* be1 = (const float*)d_in[16];
    const float* be2 = (const float*)d_in[18];
    const float* be3 = (const float*)d_in[20];
    const float* fceb = (const float*)d_in[22];
    const float* fcdb = (const float*)d_in[24];
    const float* bd0 = (const float*)d_in[26];
    const float* bd1 = (const float*)d_in[28];
    const float* bd2 = (const float*)d_in[30];
    const float* bd3 = (const float*)d_in[32];

    _Float16* W = (_Float16*)d_ws;
    size_t off = 0;
    auto alloc = [&](size_t e) { size_t o = off; off += (e + 255) & ~(size_t)255; return o; };

    const size_t oActV = alloc((size_t)5024 * 4096);   // [vertex][(b,f)]
    const size_t oActT = alloc((size_t)4096 * 5120);   // [(b,f)][vertex_padded]
    const size_t oZ    = alloc((size_t)64 * 256);
    const size_t oPart = alloc((size_t)8 * 64 * 256 * 2);   // fp32 partials (fce)
    const size_t oU3in = alloc((size_t)16384 * 32);
    const size_t oXp   = alloc((size_t)5024 * 192);
    const size_t oCvt  = alloc((size_t)(cv_off(17) + ((cv_elems(17) + 255) & ~(u64)255)));
    auto wofs = [&](int i) { return oCvt + (size_t)cv_off(i); };

    // ---- conversions ----
    cvt_x<<<dim3((64 * 5024 * 3 + 255) / 256), 256, 0, stream>>>(x, W + oXp);
    {
        CvtPtrs ps;
        ps.p[0] = (const float*)d_in[5];   // D0
        ps.p[1] = (const float*)d_in[6];   // U0
        ps.p[2] = (const float*)d_in[7];   // D1
        ps.p[3] = (const float*)d_in[8];   // U1
        ps.p[4] = (const float*)d_in[9];   // D2
        ps.p[5] = (const float*)d_in[10];  // U2
        ps.p[6] = (const float*)d_in[11];  // D3
        ps.p[7] = (const float*)d_in[12];  // U3
        ps.p[8] = (const float*)d_in[13];  // We0
        ps.p[9] = (const float*)d_in[15];  // We1
        ps.p[10] = (const float*)d_in[17]; // We2
        ps.p[11] = (const float*)d_in[19]; // We3
        ps.p[12] = (const float*)d_in[21]; // fceW
        ps.p[13] = (const float*)d_in[23]; // fcdW
        ps.p[14] = (const float*)d_in[25]; // Wd0
        ps.p[15] = (const float*)d_in[27]; // Wd1
        ps.p[16] = (const float*)d_in[29]; // Wd2
        ps.p[17] = (const float*)d_in[31]; // Wd3
        cvt_all<<<dim3(cv_start(18)), 256, 0, stream>>>(ps, W + oCvt);
    }
    hipMemsetAsync(W + oU3in, 0, (size_t)16384 * 32 * sizeof(_Float16), stream);

    #define GEMM(AM, EP, BM_, BF_, WM_, WF_, gx, gy, gz, Aw_, ars_, idx_, FiL_, Bw_, bias_, Cp_, crs_, Mp_, M_, Np_, F_, fl_, ksp_) \
        gemm_k<AM, EP, BM_, BF_, WM_, WF_><<<dim3(gx, gy, gz), 256, 0, stream>>>( \
            Aw_, ars_, idx_, FiL_, Bw_, bias_, Cp_, crs_, Mp_, M_, Np_, F_, fl_, ksp_)
    #define POOL(TBM_, OCC_, gx, gy, Aw_, Bw_, Cp_, M_, Np_, crs_) \
        pool2_k<TBM_, OCC_><<<dim3(gx, gy), 256, 0, stream>>>(Aw_, Bw_, Cp_, M_, Np_, crs_)
    #define POOLB(gx, gy, Aw_, Bw_, Cp_, M_, Np_, crs_) \
        pool2b_k<<<dim3(gx, gy), 128, 0, stream>>>(Aw_, Bw_, Cp_, M_, Np_, crs_)

    // ---- encoder ----
    GEMM(2, EPI_TR, 128, 64, 2, 2, 1, 40, 64, W + oXp, 192, s0, 0,
         W + wofs(8), be0, W + oActT, (u64)64 * 5120, 5120, 5024, 32, 64, 3, 0);
    POOLB(32, 20, W + wofs(0), W + oActT, W + oActV, 1257, 5120, 4096);
    GEMM(1, EPI_TR, 128, 64, 2, 2, 1, 10, 64, W + oActV, 4096, s1, 6,
         W + wofs(9), be1, W + oActT, (u64)64 * 1280, 1280, 1257, 576, 64, 3, 0);
    POOL(64, 3, 32, 5, W + wofs(2), W + oActT, W + oActV, 315, 1280, 4096);
    GEMM(1, EPI_TR, 128, 64, 2, 2, 2, 3, 64, W + oActV, 4096, s2, 6,
         W + wofs(10), be2, W + oActT, (u64)128 * 320, 320, 315, 576, 128, 3, 0);
    POOL(64, 3, 64, 2, W + wofs(4), W + oActT, W + oActV, 80, 320, 8192);
    GEMM(1, EPI_TR, 128, 64, 2, 2, 4, 1, 64, W + oActV, 8192, s3, 7,
         W + wofs(11), be3, W + oActT, (u64)256 * 96, 96, 80, 1152, 256, 3, 0);
    POOL(64, 3, 128, 1, W + wofs(6), W + oActT, W + oActV, 21, 96, 16384);
    // ---- bottleneck ----
    GEMM(4, EPI_PART, 64, 64, 2, 2, 4, 1, 8, W + oActV, 16384, nullptr, 8,
         W + wofs(12), nullptr, W + oPart, (u64)64 * 256, 0, 64, 5376, 256, 0, 21);
    reduce_fce<<<dim3(64), 256, 0, stream>>>((const float*)(W + oPart), fceb, W + oZ);
    GEMM(3, EPI_FCD, 64, 128, 2, 2, 42, 1, 1, W + oZ, 0, nullptr, 0,
         W + wofs(13), fcdb, W + oU3in, 0, 0, 64, 256, 5376, 0, 0);
    // ---- decoder ----
    POOL(64, 3, 128, 2, W + wofs(7), W + oU3in, W + oActV, 80, 32, 16384);
    GEMM(1, EPI_TR, 128, 64, 2, 2, 2, 1, 64, W + oActV, 16384, s3, 8,
         W + wofs(14), bd0, W + oActT, (u64)128 * 96, 96, 80, 2304, 128, 3, 0);
    POOL(64, 3, 64, 5, W + wofs(5), W + oActT, W + oActV, 315, 96, 8192);
    GEMM(1, EPI_TR, 128, 64, 2, 2, 1, 3, 64, W + oActV, 8192, s2, 7,
         W + wofs(15), bd1, W + oActT, (u64)64 * 320, 320, 315, 1152, 64, 3, 0);
    POOLB(32, 20, W + wofs(3), W + oActT, W + oActV, 1257, 320, 4096);
    GEMM(1, EPI_TR, 128, 64, 2, 2, 1, 10, 64, W + oActV, 4096, s1, 6,
         W + wofs(16), bd2, W + oActT, (u64)64 * 1280, 1280, 1257, 576, 64, 3, 0);
    POOLB(32, 79, W + wofs(1), W + oActT, W + oActV, 5024, 1280, 4096);
    GEMM(5, EPI_OUT, 128, 16, 4, 1, 1, 2512, 1, W + oActV, 4096, s0, 6,
         W + wofs(17), bd3, d_out, 0, 5024, 321536, 576, 3, 2, 0);
    #undef GEMM
    #undef POOL
    #undef POOLB
}

// Round 15
// 573.114 us; speedup vs baseline: 1.3585x; 1.0541x over previous
//
#include <hip/hip_runtime.h>
#include <math.h>

typedef __attribute__((ext_vector_type(8))) _Float16 half8;
typedef __attribute__((ext_vector_type(4))) float f32x4;
typedef unsigned long long u64;

#define BK 32

#define EPI_NAT  0
#define EPI_TR   1
#define EPI_FCD  2
#define EPI_OUT  3
#define EPI_PART 4

typedef const __attribute__((address_space(1))) void* gas1;
typedef __attribute__((address_space(3))) void* las3;

__device__ __forceinline__ void gl16(const void* g, void* l) {
    __builtin_amdgcn_global_load_lds((gas1)g, (las3)l, 16, 0, 0);
}
template<int N> __device__ __forceinline__ void vwait() {
    asm volatile("s_waitcnt vmcnt(%0)" :: "n"(N) : "memory");
}
__device__ __forceinline__ void barx() {
    asm volatile("" ::: "memory");
    __builtin_amdgcn_s_barrier();
    asm volatile("" ::: "memory");
}

// ============ pool kernel (r9 optimum): 256 thr, 4 waves (2x2), TBMx128, BK=32, 3-buf ============
template<int TBM>
__global__ __launch_bounds__(256, 3) void pool2_k(
    const _Float16* __restrict__ Aw, const _Float16* __restrict__ Bw,
    _Float16* __restrict__ Cp, int M, int Np, u64 c_rs)
{
    constexpr int FM  = TBM / 32;          // wave m-frags (WM=2)
    constexpr int LPS = TBM / 64 + 2;      // gl16 per thread per stage

    __shared__ _Float16 sA[3][TBM][BK];
    __shared__ _Float16 sB[3][128][BK];

    const int t  = threadIdx.x;
    const int m0 = blockIdx.y * TBM;
    const int f0 = blockIdx.x * 128;
    const int lane = t & 63;
    const int wid  = t >> 6;
    const int wm = wid >> 1;
    const int wf = wid & 1;
    const int lm = lane & 15;
    const int lg = lane >> 4;

    f32x4 acc[FM][4];
    #pragma unroll
    for (int i = 0; i < FM; ++i)
        #pragma unroll
        for (int j = 0; j < 4; ++j)
            acc[i][j] = (f32x4)0.0f;

    auto stage = [&](int buf, int ks) {
        #pragma unroll
        for (int j = 0; j < TBM / 64; ++j) {
            int c   = t + j * 256;
            int row = c >> 2;
            int sw  = ((c & 3) ^ ((row >> 1) & 3)) * 8;   // pre-swizzled source chunk
            int rc  = m0 + row; if (rc >= M) rc = M - 1;
            gl16(Aw + (u64)rc * Np + ks * BK + sw,
                 (_Float16*)&sA[buf][0][0] + (u64)c * 8);  // linear dest
        }
        #pragma unroll
        for (int j = 0; j < 2; ++j) {
            int c   = t + j * 256;
            int row = c >> 2;
            int sw  = ((c & 3) ^ ((row >> 1) & 3)) * 8;
            gl16(Bw + (u64)(f0 + row) * Np + ks * BK + sw,
                 (_Float16*)&sB[buf][0][0] + (u64)c * 8);
        }
    };

    auto compute = [&](int buf) {
        const int sa = (lg ^ ((lm >> 1) & 3)) * 8;        // un-swizzle on read
        half8 af[FM], bf[4];
        #pragma unroll
        for (int i = 0; i < FM; ++i)
            af[i] = *(const half8*)&sA[buf][wm * (FM * 16) + i * 16 + lm][sa];
        #pragma unroll
        for (int j = 0; j < 4; ++j)
            bf[j] = *(const half8*)&sB[buf][wf * 64 + j * 16 + lm][sa];
        #pragma unroll
        for (int i = 0; i < FM; ++i)
            #pragma unroll
            for (int j = 0; j < 4; ++j)
                acc[i][j] = __builtin_amdgcn_mfma_f32_16x16x32_f16(af[i], bf[j], acc[i][j], 0, 0, 0);
    };

    const int ke = Np / BK;
    stage(0, 0);
    if (1 < ke) stage(1, 1);
    if (2 < ke) stage(2, 2);
    int cur = 0;
    for (int ks = 0; ks < ke; ++ks) {
        int rem = ke - ks;
        if (rem >= 3)      vwait<2 * LPS>();
        else if (rem == 2) vwait<LPS>();
        else               vwait<0>();
        barx();
        compute(cur);
        barx();
        if (ks + 3 < ke) stage(cur, ks + 3);
        cur = (cur == 2) ? 0 : cur + 1;
    }

    #pragma unroll
    for (int j = 0; j < 4; ++j) {
        int fl = f0 + wf * 64 + j * 16 + lm;
        #pragma unroll
        for (int i = 0; i < FM; ++i) {
            #pragma unroll
            for (int r = 0; r < 4; ++r) {
                int m = m0 + wm * (FM * 16) + i * 16 + lg * 4 + r;
                if (m < M)
                    Cp[(u64)m * c_rs + fl] = (_Float16)acc[i][j][r];
            }
        }
    }
}

// ============ general kernel (sconv / fc) — r9 proven ============
// AMODE: 1 sconv gather (idx via LDS), 2 sconv0 (Fi=3, nk=1),
//        3 fc, 4 fc-enc split-K, 5 sconv rows-folded [Wd3]
template<int AMODE, int EPI, int TBM, int TBF, int WM, int WF>
__global__ __launch_bounds__(256) void gemm_k(
    const _Float16* __restrict__ Aw, u64 a_rs,
    const int* __restrict__ idx, int FiLog,
    const _Float16* __restrict__ Bw,
    const float* __restrict__ bias,
    void* __restrict__ Cp, u64 c_rs, int Mp_out,
    int M, int Np, int F, int flags, int ksp)   // flags: bit0 ELU, bit1 zeroLast
{
    constexpr int FM = TBM / WM / 16;
    constexpr int FF = TBF / WF / 16;
    constexpr int LPS_A = TBM / 64;
    constexpr bool BSM = (TBF < 64);
    constexpr int LPS_B = BSM ? 0 : TBF / 64;
    constexpr int LW0 = LPS_A + (BSM ? 1 : LPS_B);
    constexpr int LWX = LPS_A + LPS_B;
    constexpr int NI = (AMODE == 1) ? TBM : 2;

    __shared__ _Float16 sA[3][TBM][BK];
    __shared__ _Float16 sB[3][TBF][BK];
    __shared__ int sIdx[NI][9];

    const int t  = threadIdx.x;
    const int b  = blockIdx.z;
    const int m0 = blockIdx.y * TBM;
    const int f0 = blockIdx.x * TBF;
    const int lane = t & 63;
    const int wid  = t >> 6;
    const int wm = wid / WF;
    const int wf = wid % WF;
    const int lm = lane & 15;
    const int lg = lane >> 4;
    const int Fi = 1 << FiLog;

    f32x4 acc[FM][FF];
    #pragma unroll
    for (int i = 0; i < FM; ++i)
        #pragma unroll
        for (int j = 0; j < FF; ++j)
            acc[i][j] = (f32x4)0.0f;

    if constexpr (AMODE == 1) {
        for (int i = t; i < TBM * 9; i += 256) {
            int r = i / 9, k = i - r * 9;
            int rc = m0 + r; if (rc >= M) rc = M - 1;
            sIdx[r][k] = idx[rc * 9 + k];
        }
        __syncthreads();
    } else if constexpr (AMODE == 5) {
        if (t < 18) {
            int r = t / 9, k = t - r * 9;
            sIdx[r][k] = idx[((m0 >> 6) + r) * 9 + k];
        }
        __syncthreads();
    }

    auto stage = [&](int buf, int ks) {
        if constexpr (AMODE != 2) {
            #pragma unroll
            for (int j = 0; j < LPS_A; ++j) {
                int c   = t + j * 256;
                int row = c >> 2;
                int sw  = ((c & 3) ^ ((row >> 1) & 3)) * 8;   // pre-swizzled source chunk
                int col = ks * BK + sw;
                const _Float16* src;
                if constexpr (AMODE == 3) {
                    int rc = m0 + row; if (rc >= M) rc = M - 1;
                    src = Aw + (u64)rc * Np + col;
                } else if constexpr (AMODE == 1) {
                    int k = col >> FiLog, fi = col & (Fi - 1);
                    src = Aw + (u64)sIdx[row][k] * a_rs + b * Fi + fi;
                } else if constexpr (AMODE == 4) {
                    int k = col >> FiLog, fi = col & (Fi - 1);
                    src = Aw + (u64)k * a_rs + (m0 + row) * Fi + fi;
                } else {  // 5
                    int k = col >> FiLog, fi = col & (Fi - 1);
                    int bb = (m0 + row) & 63;
                    src = Aw + (u64)sIdx[row >> 6][k] * a_rs + bb * Fi + fi;
                }
                gl16(src, &sA[buf][row][(c & 3) * 8]);   // linear dest
            }
        }
        if constexpr (!BSM) {
            #pragma unroll
            for (int j = 0; j < LPS_B; ++j) {
                int c   = t + j * 256;
                int row = c >> 2;
                int sw  = ((c & 3) ^ ((row >> 1) & 3)) * 8;
                gl16(Bw + (u64)(f0 + row) * Np + ks * BK + sw, &sB[buf][row][(c & 3) * 8]);
            }
        } else {
            if (wid == 0) {
                int c   = t;
                int row = c >> 2;
                int sw  = ((c & 3) ^ ((row >> 1) & 3)) * 8;
                gl16(Bw + (u64)(f0 + row) * Np + ks * BK + sw, &sB[buf][row][(c & 3) * 8]);
            }
        }
    };

    auto compute = [&](int buf) {
        const int sa = (lg ^ ((lm >> 1) & 3)) * 8;   // un-swizzle on read
        half8 af[FM], bf[FF];
        #pragma unroll
        for (int i = 0; i < FM; ++i)
            af[i] = *(const half8*)&sA[buf][wm * (FM * 16) + i * 16 + lm][sa];
        #pragma unroll
        for (int j = 0; j < FF; ++j)
            bf[j] = *(const half8*)&sB[buf][wf * (FF * 16) + j * 16 + lm][sa];
        #pragma unroll
        for (int i = 0; i < FM; ++i)
            #pragma unroll
            for (int j = 0; j < FF; ++j)
                acc[i][j] = __builtin_amdgcn_mfma_f32_16x16x32_f16(af[i], bf[j], acc[i][j], 0, 0, 0);
    };

    if constexpr (AMODE == 2) {
        stage(0, 0);   // B only
        {
            int row = t >> 1;
            int base = (t & 1) * 16;
            int rg = m0 + row;
            #pragma unroll
            for (int q = 0; q < 16; ++q) {
                int n = base + q;
                _Float16 val = (_Float16)0.f;
                if (rg < M && n < 27) {
                    int k = n / 3, fi = n - k * 3;
                    val = Aw[(u64)idx[rg * 9 + k] * a_rs + b * 3 + fi];
                }
                int ch = (n >> 3) ^ ((row >> 1) & 3);
                sA[0][row][ch * 8 + (n & 7)] = val;   // store swizzled
            }
        }
        __syncthreads();
        compute(0);
    } else {
        int kb = 0, ke = Np / BK;
        if constexpr (AMODE == 4) { kb = b * ksp; ke = kb + ksp; }
        stage(0, kb);
        if (kb + 1 < ke) stage(1, kb + 1);
        if (kb + 2 < ke) stage(2, kb + 2);
        int cur = 0;
        for (int ks = kb; ks < ke; ++ks) {
            int rem = ke - ks;
            if (rem >= 3) {
                if constexpr (LW0 == LWX) vwait<2 * LW0>();
                else { if (wid == 0) vwait<2 * LW0>(); else vwait<2 * LWX>(); }
            } else if (rem == 2) {
                if constexpr (LW0 == LWX) vwait<LW0>();
                else { if (wid == 0) vwait<LW0>(); else vwait<LWX>(); }
            } else {
                vwait<0>();
            }
            barx();
            compute(cur);
            barx();
            if (ks + 3 < ke) stage(cur, ks + 3);
            cur = (cur == 2) ? 0 : cur + 1;
        }
    }

    #pragma unroll
    for (int j = 0; j < FF; ++j) {
        int fl = f0 + wf * (FF * 16) + j * 16 + lm;
        float bv = 0.f;
        if (bias != nullptr && fl < F) bv = bias[fl];
        #pragma unroll
        for (int i = 0; i < FM; ++i) {
            #pragma unroll
            for (int r = 0; r < 4; ++r) {
                int m = m0 + wm * (FM * 16) + i * 16 + lg * 4 + r;
                float v = acc[i][j][r] + bv;
                if (flags & 1) v = (v > 0.f) ? v : expm1f(v);
                if constexpr (EPI == EPI_NAT) {
                    if (m < M && fl < F)
                        ((_Float16*)Cp)[(u64)m * c_rs + fl] = (_Float16)v;
                } else if constexpr (EPI == EPI_TR) {
                    if (m < Mp_out && fl < F) {
                        float o = (m < M && !((flags & 2) && m == M - 1)) ? v : 0.f;
                        ((_Float16*)Cp)[(u64)b * c_rs + (u64)fl * Mp_out + m] = (_Float16)o;
                    }
                } else if constexpr (EPI == EPI_FCD) {
                    if (m < M && fl < F)
                        ((_Float16*)Cp)[((u64)m * 256 + (fl & 255)) * 32 + (fl >> 8)] = (_Float16)v;
                } else if constexpr (EPI == EPI_PART) {
                    if (m < M && fl < F)
                        ((float*)Cp)[(u64)b * c_rs + (u64)m * F + fl] = v;
                } else {  // EPI_OUT (rows folded: m = v*64+b)
                    if (m < M && fl < F) {
                        int vo = m >> 6, bb = m & 63;
                        float o = ((flags & 2) && vo == Mp_out - 1) ? 0.f : v;
                        ((float*)Cp)[((u64)bb * Mp_out + vo) * 3 + fl] = o;
                    }
                }
            }
        }
    }
}

// ---- fused weight conversion ----
struct CvtPtrs { const float* p[18]; };

constexpr int CV_R[18]  = {1257,5024,315,1257,80,315,21,80,  64,64,128,256,256,5376,128,64,64,16};
constexpr int CV_N[18]  = {5024,1257,1257,315,315,80,80,21,  27,576,576,1152,5376,256,2304,1152,576,576};
constexpr int CV_NP[18] = {5120,1280,1280,320,320,96,96,32,  32,576,576,1152,5376,256,2304,1152,576,576};
constexpr int CV_F[18]  = {0,0,0,0,0,0,0,0,  64,64,128,256,256,5376,128,64,64,3};

constexpr u64 cv_elems(int i) { return (u64)CV_R[i] * CV_NP[i]; }
constexpr u64 cv_off(int i) { u64 o = 0; for (int j = 0; j < i; ++j) o += (cv_elems(j) + 255) & ~(u64)255; return o; }
constexpr int cv_blk(int i) { return (int)((cv_elems(i) + 255) >> 8); }
constexpr int cv_start(int i) { int s = 0; for (int j = 0; j < i; ++j) s += cv_blk(j); return s; }

__global__ __launch_bounds__(256) void cvt_all(CvtPtrs ps, _Float16* __restrict__ dst)
{
    const int bx = blockIdx.x, t = threadIdx.x;
    #pragma unroll
    for (int i = 0; i < 18; ++i) {
        if (bx >= cv_start(i) && bx < cv_start(i + 1)) {
            const u64 e = (u64)(bx - cv_start(i)) * 256 + t;
            if (e < cv_elems(i)) {
                const int NP = CV_NP[i], N = CV_N[i], Fo = CV_F[i];
                int row = (int)(e / (u64)NP);
                int col = (int)(e - (u64)row * NP);
                float v = 0.f;
                const float* s = ps.p[i];
                if (Fo == 0) { if (col < N) v = s[(u64)row * N + col]; }
                else         { if (col < N && row < Fo) v = s[(u64)col * Fo + row]; }
                dst[cv_off(i) + e] = (_Float16)v;
            }
        }
    }
}

__global__ void cvt_x(const float* __restrict__ src, _Float16* __restrict__ dst)
{
    int i = blockIdx.x * 256 + threadIdx.x;
    if (i >= 64 * 5024 * 3) return;
    int v = i / 192;
    int r = i - v * 192;
    int b = r / 3, c = r - b * 3;
    dst[i] = (_Float16)src[((u64)b * 5024 + v) * 3 + c];
}

__global__ void reduce_fce(const float* __restrict__ part, const float* __restrict__ bias,
                           _Float16* __restrict__ z)
{
    int i = blockIdx.x * 256 + threadIdx.x;  // 64*256
    int fl = i & 255;
    float s = bias[fl];
    #pragma unroll
    for (int p = 0; p < 8; ++p) s += part[(u64)p * 16384 + i];
    z[i] = (_Float16)s;
}

extern "C" void kernel_launch(void* const* d_in, const int* in_sizes, int n_in,
                              void* d_out, int out_size, void* d_ws, size_t ws_size,
                              hipStream_t stream)
{
    const float* x  = (const float*)d_in[0];
    const int* s0 = (const int*)d_in[1];
    const int* s1 = (const int*)d_in[2];
    const int* s2 = (const int*)d_in[3];
    const int* s3 = (const int*)d_in[4];
    const float* be0 = (const float*)d_in[14];
    const float* be1 = (const float*)d_in[16];
    const float* be2 = (const float*)d_in[18];
    const float* be3 = (const float*)d_in[20];
    const float* fceb = (const float*)d_in[22];
    const float* fcdb = (const float*)d_in[24];
    const float* bd0 = (const float*)d_in[26];
    const float* bd1 = (const float*)d_in[28];
    const float* bd2 = (const float*)d_in[30];
    const float* bd3 = (const float*)d_in[32];

    _Float16* W = (_Float16*)d_ws;
    size_t off = 0;
    auto alloc = [&](size_t e) { size_t o = off; off += (e + 255) & ~(size_t)255; return o; };

    const size_t oActV = alloc((size_t)5024 * 4096);   // [vertex][(b,f)]
    const size_t oActT = alloc((size_t)4096 * 5120);   // [(b,f)][vertex_padded]
    const size_t oZ    = alloc((size_t)64 * 256);
    const size_t oPart = alloc((size_t)8 * 64 * 256 * 2);   // fp32 partials (fce)
    const size_t oU3in = alloc((size_t)16384 * 32);
    const size_t oXp   = alloc((size_t)5024 * 192);
    const size_t oCvt  = alloc((size_t)(cv_off(17) + ((cv_elems(17) + 255) & ~(u64)255)));
    auto wofs = [&](int i) { return oCvt + (size_t)cv_off(i); };

    // ---- conversions ----
    cvt_x<<<dim3((64 * 5024 * 3 + 255) / 256), 256, 0, stream>>>(x, W + oXp);
    {
        CvtPtrs ps;
        ps.p[0] = (const float*)d_in[5];   // D0
        ps.p[1] = (const float*)d_in[6];   // U0
        ps.p[2] = (const float*)d_in[7];   // D1
        ps.p[3] = (const float*)d_in[8];   // U1
        ps.p[4] = (const float*)d_in[9];   // D2
        ps.p[5] = (const float*)d_in[10];  // U2
        ps.p[6] = (const float*)d_in[11];  // D3
        ps.p[7] = (const float*)d_in[12];  // U3
        ps.p[8] = (const float*)d_in[13];  // We0
        ps.p[9] = (const float*)d_in[15];  // We1
        ps.p[10] = (const float*)d_in[17]; // We2
        ps.p[11] = (const float*)d_in[19]; // We3
        ps.p[12] = (const float*)d_in[21]; // fceW
        ps.p[13] = (const float*)d_in[23]; // fcdW
        ps.p[14] = (const float*)d_in[25]; // Wd0
        ps.p[15] = (const float*)d_in[27]; // Wd1
        ps.p[16] = (const float*)d_in[29]; // Wd2
        ps.p[17] = (const float*)d_in[31]; // Wd3
        cvt_all<<<dim3(cv_start(18)), 256, 0, stream>>>(ps, W + oCvt);
    }
    hipMemsetAsync(W + oU3in, 0, (size_t)16384 * 32 * sizeof(_Float16), stream);

    #define GEMM(AM, EP, BM_, BF_, WM_, WF_, gx, gy, gz, Aw_, ars_, idx_, FiL_, Bw_, bias_, Cp_, crs_, Mp_, M_, Np_, F_, fl_, ksp_) \
        gemm_k<AM, EP, BM_, BF_, WM_, WF_><<<dim3(gx, gy, gz), 256, 0, stream>>>( \
            Aw_, ars_, idx_, FiL_, Bw_, bias_, Cp_, crs_, Mp_, M_, Np_, F_, fl_, ksp_)
    #define POOL(TBM_, gx, gy, Aw_, Bw_, Cp_, M_, Np_, crs_) \
        pool2_k<TBM_><<<dim3(gx, gy), 256, 0, stream>>>(Aw_, Bw_, Cp_, M_, Np_, crs_)

    // ---- encoder ----
    GEMM(2, EPI_TR, 128, 64, 2, 2, 1, 40, 64, W + oXp, 192, s0, 0,
         W + wofs(8), be0, W + oActT, (u64)64 * 5120, 5120, 5024, 32, 64, 3, 0);
    POOL(64, 32, 20, W + wofs(0), W + oActT, W + oActV, 1257, 5120, 4096);
    GEMM(1, EPI_TR, 128, 64, 2, 2, 1, 10, 64, W + oActV, 4096, s1, 6,
         W + wofs(9), be1, W + oActT, (u64)64 * 1280, 1280, 1257, 576, 64, 3, 0);
    POOL(64, 32, 5, W + wofs(2), W + oActT, W + oActV, 315, 1280, 4096);
    GEMM(1, EPI_TR, 128, 64, 2, 2, 2, 3, 64, W + oActV, 4096, s2, 6,
         W + wofs(10), be2, W + oActT, (u64)128 * 320, 320, 315, 576, 128, 3, 0);
    POOL(64, 64, 2, W + wofs(4), W + oActT, W + oActV, 80, 320, 8192);
    GEMM(1, EPI_TR, 128, 64, 2, 2, 4, 1, 64, W + oActV, 8192, s3, 7,
         W + wofs(11), be3, W + oActT, (u64)256 * 96, 96, 80, 1152, 256, 3, 0);
    POOL(64, 128, 1, W + wofs(6), W + oActT, W + oActV, 21, 96, 16384);
    // ---- bottleneck ----
    GEMM(4, EPI_PART, 64, 64, 2, 2, 4, 1, 8, W + oActV, 16384, nullptr, 8,
         W + wofs(12), nullptr, W + oPart, (u64)64 * 256, 0, 64, 5376, 256, 0, 21);
    reduce_fce<<<dim3(64), 256, 0, stream>>>((const float*)(W + oPart), fceb, W + oZ);
    GEMM(3, EPI_FCD, 64, 128, 2, 2, 42, 1, 1, W + oZ, 0, nullptr, 0,
         W + wofs(13), fcdb, W + oU3in, 0, 0, 64, 256, 5376, 0, 0);
    // ---- decoder ----
    POOL(64, 128, 2, W + wofs(7), W + oU3in, W + oActV, 80, 32, 16384);
    GEMM(1, EPI_TR, 128, 64, 2, 2, 2, 1, 64, W + oActV, 16384, s3, 8,
         W + wofs(14), bd0, W + oActT, (u64)128 * 96, 96, 80, 2304, 128, 3, 0);
    POOL(64, 64, 5, W + wofs(5), W + oActT, W + oActV, 315, 96, 8192);
    GEMM(1, EPI_TR, 128, 64, 2, 2, 1, 3, 64, W + oActV, 8192, s2, 7,
         W + wofs(15), bd1, W + oActT, (u64)64 * 320, 320, 315, 1152, 64, 3, 0);
    POOL(64, 32, 20, W + wofs(3), W + oActT, W + oActV, 1257, 320, 4096);
    GEMM(1, EPI_TR, 128, 64, 2, 2, 1, 10, 64, W + oActV, 4096, s1, 6,
         W + wofs(16), bd2, W + oActT, (u64)64 * 1280, 1280, 1257, 576, 64, 3, 0);
    POOL(128, 32, 40, W + wofs(1), W + oActT, W + oActV, 5024, 1280, 4096);
    GEMM(5, EPI_OUT, 128, 16, 4, 1, 1, 2512, 1, W + oActV, 4096, s0, 6,
         W + wofs(17), bd3, d_out, 0, 5024, 321536, 576, 3, 2, 0);
    #undef GEMM
    #undef POOL
}

// Round 16
// 552.757 us; speedup vs baseline: 1.4085x; 1.0368x over previous
//
#include <hip/hip_runtime.h>
#include <math.h>

typedef __attribute__((ext_vector_type(8))) _Float16 half8;
typedef __attribute__((ext_vector_type(4))) float f32x4;
typedef unsigned long long u64;

#define BK 32

#define EPI_NAT  0
#define EPI_TR   1
#define EPI_FCD  2
#define EPI_OUT  3
#define EPI_PART 4

typedef const __attribute__((address_space(1))) void* gas1;
typedef __attribute__((address_space(3))) void* las3;

__device__ __forceinline__ void gl16(const void* g, void* l) {
    __builtin_amdgcn_global_load_lds((gas1)g, (las3)l, 16, 0, 0);
}
template<int N> __device__ __forceinline__ void vwait() {
    asm volatile("s_waitcnt vmcnt(%0)" :: "n"(N) : "memory");
}
__device__ __forceinline__ void barx() {
    asm volatile("" ::: "memory");
    __builtin_amdgcn_s_barrier();
    asm volatile("" ::: "memory");
}

// ============ pool4: 256 thr, 4 waves (2x2), 64x128 tile, BK=64, 2-buf ============
// Halves barrier/vmcnt EVENTS per K-element vs pool2 (m233: stage+wait+barrier is the
// dominant 2-phase cost). 48KB LDS -> occ 3. r7-proven (c&7)^(row&7) swizzle (conflicts=0).
__global__ __launch_bounds__(256, 3) void pool4_k(
    const _Float16* __restrict__ Aw, const _Float16* __restrict__ Bw,
    _Float16* __restrict__ Cp, int M, int Np, u64 c_rs)
{
    constexpr int LPS = 6;   // 2 A-chunks + 4 B-chunks per thread per stage

    __shared__ _Float16 sA[2][64][64];
    __shared__ _Float16 sB[2][128][64];

    const int t  = threadIdx.x;
    const int m0 = blockIdx.y * 64;
    const int f0 = blockIdx.x * 128;
    const int lane = t & 63;
    const int wid  = t >> 6;
    const int wm = wid >> 1;     // 0..1 (32-row halves)
    const int wf = wid & 1;      // 0..1 (64-col halves)
    const int lm = lane & 15;
    const int lg = lane >> 4;

    f32x4 acc[2][4];
    #pragma unroll
    for (int i = 0; i < 2; ++i)
        #pragma unroll
        for (int j = 0; j < 4; ++j)
            acc[i][j] = (f32x4)0.0f;

    auto stage = [&](int buf, int ks) {
        #pragma unroll
        for (int j = 0; j < 2; ++j) {         // A: 64 rows x 64 cols = 512 chunks
            int c   = t + j * 256;
            int row = c >> 3;
            int ch  = (c & 7) ^ (row & 7);    // pre-swizzled source chunk
            int rc  = m0 + row; if (rc >= M) rc = M - 1;
            gl16(Aw + (u64)rc * Np + ks * 64 + ch * 8,
                 (_Float16*)&sA[buf][0][0] + (u64)c * 8);  // linear dest
        }
        #pragma unroll
        for (int j = 0; j < 4; ++j) {         // B: 128 rows x 64 cols = 1024 chunks
            int c   = t + j * 256;
            int row = c >> 3;
            int ch  = (c & 7) ^ (row & 7);
            gl16(Bw + (u64)(f0 + row) * Np + ks * 64 + ch * 8,
                 (_Float16*)&sB[buf][0][0] + (u64)c * 8);
        }
    };

    auto compute = [&](int buf) {
        #pragma unroll
        for (int kh = 0; kh < 2; ++kh) {
            const int ch = (kh * 4 + lg) ^ (lm & 7);   // un-swizzle on read
            half8 af[2], bf[4];
            #pragma unroll
            for (int i = 0; i < 2; ++i)
                af[i] = *(const half8*)&sA[buf][wm * 32 + i * 16 + lm][ch * 8];
            #pragma unroll
            for (int j = 0; j < 4; ++j)
                bf[j] = *(const half8*)&sB[buf][wf * 64 + j * 16 + lm][ch * 8];
            #pragma unroll
            for (int i = 0; i < 2; ++i)
                #pragma unroll
                for (int j = 0; j < 4; ++j)
                    acc[i][j] = __builtin_amdgcn_mfma_f32_16x16x32_f16(af[i], bf[j], acc[i][j], 0, 0, 0);
        }
    };

    const int ke = Np / 64;
    stage(0, 0);
    if (1 < ke) stage(1, 1);
    for (int ks = 0; ks < ke; ++ks) {
        if (ke - ks >= 2) vwait<LPS>();   // oldest stage (buf ks&1) landed; next may fly
        else              vwait<0>();
        barx();
        compute(ks & 1);
        barx();
        if (ks + 2 < ke) stage(ks & 1, ks + 2);
    }

    #pragma unroll
    for (int j = 0; j < 4; ++j) {
        int fl = f0 + wf * 64 + j * 16 + lm;
        #pragma unroll
        for (int i = 0; i < 2; ++i) {
            #pragma unroll
            for (int r = 0; r < 4; ++r) {
                int m = m0 + wm * 32 + i * 16 + lg * 4 + r;
                if (m < M)
                    Cp[(u64)m * c_rs + fl] = (_Float16)acc[i][j][r];
            }
        }
    }
}

// ============ pool kernel (r9 optimum): 256 thr, 4 waves (2x2), TBMx128, BK=32, 3-buf ============
template<int TBM>
__global__ __launch_bounds__(256, 3) void pool2_k(
    const _Float16* __restrict__ Aw, const _Float16* __restrict__ Bw,
    _Float16* __restrict__ Cp, int M, int Np, u64 c_rs)
{
    constexpr int FM  = TBM / 32;          // wave m-frags (WM=2)
    constexpr int LPS = TBM / 64 + 2;      // gl16 per thread per stage

    __shared__ _Float16 sA[3][TBM][BK];
    __shared__ _Float16 sB[3][128][BK];

    const int t  = threadIdx.x;
    const int m0 = blockIdx.y * TBM;
    const int f0 = blockIdx.x * 128;
    const int lane = t & 63;
    const int wid  = t >> 6;
    const int wm = wid >> 1;
    const int wf = wid & 1;
    const int lm = lane & 15;
    const int lg = lane >> 4;

    f32x4 acc[FM][4];
    #pragma unroll
    for (int i = 0; i < FM; ++i)
        #pragma unroll
        for (int j = 0; j < 4; ++j)
            acc[i][j] = (f32x4)0.0f;

    auto stage = [&](int buf, int ks) {
        #pragma unroll
        for (int j = 0; j < TBM / 64; ++j) {
            int c   = t + j * 256;
            int row = c >> 2;
            int sw  = ((c & 3) ^ ((row >> 1) & 3)) * 8;   // pre-swizzled source chunk
            int rc  = m0 + row; if (rc >= M) rc = M - 1;
            gl16(Aw + (u64)rc * Np + ks * BK + sw,
                 (_Float16*)&sA[buf][0][0] + (u64)c * 8);  // linear dest
        }
        #pragma unroll
        for (int j = 0; j < 2; ++j) {
            int c   = t + j * 256;
            int row = c >> 2;
            int sw  = ((c & 3) ^ ((row >> 1) & 3)) * 8;
            gl16(Bw + (u64)(f0 + row) * Np + ks * BK + sw,
                 (_Float16*)&sB[buf][0][0] + (u64)c * 8);
        }
    };

    auto compute = [&](int buf) {
        const int sa = (lg ^ ((lm >> 1) & 3)) * 8;        // un-swizzle on read
        half8 af[FM], bf[4];
        #pragma unroll
        for (int i = 0; i < FM; ++i)
            af[i] = *(const half8*)&sA[buf][wm * (FM * 16) + i * 16 + lm][sa];
        #pragma unroll
        for (int j = 0; j < 4; ++j)
            bf[j] = *(const half8*)&sB[buf][wf * 64 + j * 16 + lm][sa];
        #pragma unroll
        for (int i = 0; i < FM; ++i)
            #pragma unroll
            for (int j = 0; j < 4; ++j)
                acc[i][j] = __builtin_amdgcn_mfma_f32_16x16x32_f16(af[i], bf[j], acc[i][j], 0, 0, 0);
    };

    const int ke = Np / BK;
    stage(0, 0);
    if (1 < ke) stage(1, 1);
    if (2 < ke) stage(2, 2);
    int cur = 0;
    for (int ks = 0; ks < ke; ++ks) {
        int rem = ke - ks;
        if (rem >= 3)      vwait<2 * LPS>();
        else if (rem == 2) vwait<LPS>();
        else               vwait<0>();
        barx();
        compute(cur);
        barx();
        if (ks + 3 < ke) stage(cur, ks + 3);
        cur = (cur == 2) ? 0 : cur + 1;
    }

    #pragma unroll
    for (int j = 0; j < 4; ++j) {
        int fl = f0 + wf * 64 + j * 16 + lm;
        #pragma unroll
        for (int i = 0; i < FM; ++i) {
            #pragma unroll
            for (int r = 0; r < 4; ++r) {
                int m = m0 + wm * (FM * 16) + i * 16 + lg * 4 + r;
                if (m < M)
                    Cp[(u64)m * c_rs + fl] = (_Float16)acc[i][j][r];
            }
        }
    }
}

// ============ general kernel (sconv / fc) — r9 proven ============
// AMODE: 1 sconv gather (idx via LDS), 2 sconv0 (Fi=3, nk=1),
//        3 fc, 4 fc-enc split-K, 5 sconv rows-folded [Wd3]
template<int AMODE, int EPI, int TBM, int TBF, int WM, int WF>
__global__ __launch_bounds__(256) void gemm_k(
    const _Float16* __restrict__ Aw, u64 a_rs,
    const int* __restrict__ idx, int FiLog,
    const _Float16* __restrict__ Bw,
    const float* __restrict__ bias,
    void* __restrict__ Cp, u64 c_rs, int Mp_out,
    int M, int Np, int F, int flags, int ksp)   // flags: bit0 ELU, bit1 zeroLast
{
    constexpr int FM = TBM / WM / 16;
    constexpr int FF = TBF / WF / 16;
    constexpr int LPS_A = TBM / 64;
    constexpr bool BSM = (TBF < 64);
    constexpr int LPS_B = BSM ? 0 : TBF / 64;
    constexpr int LW0 = LPS_A + (BSM ? 1 : LPS_B);
    constexpr int LWX = LPS_A + LPS_B;
    constexpr int NI = (AMODE == 1) ? TBM : 2;

    __shared__ _Float16 sA[3][TBM][BK];
    __shared__ _Float16 sB[3][TBF][BK];
    __shared__ int sIdx[NI][9];

    const int t  = threadIdx.x;
    const int b  = blockIdx.z;
    const int m0 = blockIdx.y * TBM;
    const int f0 = blockIdx.x * TBF;
    const int lane = t & 63;
    const int wid  = t >> 6;
    const int wm = wid / WF;
    const int wf = wid % WF;
    const int lm = lane & 15;
    const int lg = lane >> 4;
    const int Fi = 1 << FiLog;

    f32x4 acc[FM][FF];
    #pragma unroll
    for (int i = 0; i < FM; ++i)
        #pragma unroll
        for (int j = 0; j < FF; ++j)
            acc[i][j] = (f32x4)0.0f;

    if constexpr (AMODE == 1) {
        for (int i = t; i < TBM * 9; i += 256) {
            int r = i / 9, k = i - r * 9;
            int rc = m0 + r; if (rc >= M) rc = M - 1;
            sIdx[r][k] = idx[rc * 9 + k];
        }
        __syncthreads();
    } else if constexpr (AMODE == 5) {
        if (t < 18) {
            int r = t / 9, k = t - r * 9;
            sIdx[r][k] = idx[((m0 >> 6) + r) * 9 + k];
        }
        __syncthreads();
    }

    auto stage = [&](int buf, int ks) {
        if constexpr (AMODE != 2) {
            #pragma unroll
            for (int j = 0; j < LPS_A; ++j) {
                int c   = t + j * 256;
                int row = c >> 2;
                int sw  = ((c & 3) ^ ((row >> 1) & 3)) * 8;   // pre-swizzled source chunk
                int col = ks * BK + sw;
                const _Float16* src;
                if constexpr (AMODE == 3) {
                    int rc = m0 + row; if (rc >= M) rc = M - 1;
                    src = Aw + (u64)rc * Np + col;
                } else if constexpr (AMODE == 1) {
                    int k = col >> FiLog, fi = col & (Fi - 1);
                    src = Aw + (u64)sIdx[row][k] * a_rs + b * Fi + fi;
                } else if constexpr (AMODE == 4) {
                    int k = col >> FiLog, fi = col & (Fi - 1);
                    src = Aw + (u64)k * a_rs + (m0 + row) * Fi + fi;
                } else {  // 5
                    int k = col >> FiLog, fi = col & (Fi - 1);
                    int bb = (m0 + row) & 63;
                    src = Aw + (u64)sIdx[row >> 6][k] * a_rs + bb * Fi + fi;
                }
                gl16(src, &sA[buf][row][(c & 3) * 8]);   // linear dest
            }
        }
        if constexpr (!BSM) {
            #pragma unroll
            for (int j = 0; j < LPS_B; ++j) {
                int c   = t + j * 256;
                int row = c >> 2;
                int sw  = ((c & 3) ^ ((row >> 1) & 3)) * 8;
                gl16(Bw + (u64)(f0 + row) * Np + ks * BK + sw, &sB[buf][row][(c & 3) * 8]);
            }
        } else {
            if (wid == 0) {
                int c   = t;
                int row = c >> 2;
                int sw  = ((c & 3) ^ ((row >> 1) & 3)) * 8;
                gl16(Bw + (u64)(f0 + row) * Np + ks * BK + sw, &sB[buf][row][(c & 3) * 8]);
            }
        }
    };

    auto compute = [&](int buf) {
        const int sa = (lg ^ ((lm >> 1) & 3)) * 8;   // un-swizzle on read
        half8 af[FM], bf[FF];
        #pragma unroll
        for (int i = 0; i < FM; ++i)
            af[i] = *(const half8*)&sA[buf][wm * (FM * 16) + i * 16 + lm][sa];
        #pragma unroll
        for (int j = 0; j < FF; ++j)
            bf[j] = *(const half8*)&sB[buf][wf * (FF * 16) + j * 16 + lm][sa];
        #pragma unroll
        for (int i = 0; i < FM; ++i)
            #pragma unroll
            for (int j = 0; j < FF; ++j)
                acc[i][j] = __builtin_amdgcn_mfma_f32_16x16x32_f16(af[i], bf[j], acc[i][j], 0, 0, 0);
    };

    if constexpr (AMODE == 2) {
        stage(0, 0);   // B only
        {
            int row = t >> 1;
            int base = (t & 1) * 16;
            int rg = m0 + row;
            #pragma unroll
            for (int q = 0; q < 16; ++q) {
                int n = base + q;
                _Float16 val = (_Float16)0.f;
                if (rg < M && n < 27) {
                    int k = n / 3, fi = n - k * 3;
                    val = Aw[(u64)idx[rg * 9 + k] * a_rs + b * 3 + fi];
                }
                int ch = (n >> 3) ^ ((row >> 1) & 3);
                sA[0][row][ch * 8 + (n & 7)] = val;   // store swizzled
            }
        }
        __syncthreads();
        compute(0);
    } else {
        int kb = 0, ke = Np / BK;
        if constexpr (AMODE == 4) { kb = b * ksp; ke = kb + ksp; }
        stage(0, kb);
        if (kb + 1 < ke) stage(1, kb + 1);
        if (kb + 2 < ke) stage(2, kb + 2);
        int cur = 0;
        for (int ks = kb; ks < ke; ++ks) {
            int rem = ke - ks;
            if (rem >= 3) {
                if constexpr (LW0 == LWX) vwait<2 * LW0>();
                else { if (wid == 0) vwait<2 * LW0>(); else vwait<2 * LWX>(); }
            } else if (rem == 2) {
                if constexpr (LW0 == LWX) vwait<LW0>();
                else { if (wid == 0) vwait<LW0>(); else vwait<LWX>(); }
            } else {
                vwait<0>();
            }
            barx();
            compute(cur);
            barx();
            if (ks + 3 < ke) stage(cur, ks + 3);
            cur = (cur == 2) ? 0 : cur + 1;
        }
    }

    #pragma unroll
    for (int j = 0; j < FF; ++j) {
        int fl = f0 + wf * (FF * 16) + j * 16 + lm;
        float bv = 0.f;
        if (bias != nullptr && fl < F) bv = bias[fl];
        #pragma unroll
        for (int i = 0; i < FM; ++i) {
            #pragma unroll
            for (int r = 0; r < 4; ++r) {
                int m = m0 + wm * (FM * 16) + i * 16 + lg * 4 + r;
                float v = acc[i][j][r] + bv;
                if (flags & 1) v = (v > 0.f) ? v : expm1f(v);
                if constexpr (EPI == EPI_NAT) {
                    if (m < M && fl < F)
                        ((_Float16*)Cp)[(u64)m * c_rs + fl] = (_Float16)v;
                } else if constexpr (EPI == EPI_TR) {
                    if (m < Mp_out && fl < F) {
                        float o = (m < M && !((flags & 2) && m == M - 1)) ? v : 0.f;
                        ((_Float16*)Cp)[(u64)b * c_rs + (u64)fl * Mp_out + m] = (_Float16)o;
                    }
                } else if constexpr (EPI == EPI_FCD) {
                    if (m < M && fl < F)
                        ((_Float16*)Cp)[((u64)m * 256 + (fl & 255)) * 32 + (fl >> 8)] = (_Float16)v;
                } else if constexpr (EPI == EPI_PART) {
                    if (m < M && fl < F)
                        ((float*)Cp)[(u64)b * c_rs + (u64)m * F + fl] = v;
                } else {  // EPI_OUT (rows folded: m = v*64+b)
                    if (m < M && fl < F) {
                        int vo = m >> 6, bb = m & 63;
                        float o = ((flags & 2) && vo == Mp_out - 1) ? 0.f : v;
                        ((float*)Cp)[((u64)bb * Mp_out + vo) * 3 + fl] = o;
                    }
                }
            }
        }
    }
}

// ---- fused weight conversion ----
struct CvtPtrs { const float* p[18]; };

constexpr int CV_R[18]  = {1257,5024,315,1257,80,315,21,80,  64,64,128,256,256,5376,128,64,64,16};
constexpr int CV_N[18]  = {5024,1257,1257,315,315,80,80,21,  27,576,576,1152,5376,256,2304,1152,576,576};
constexpr int CV_NP[18] = {5120,1280,1280,320,320,96,96,32,  32,576,576,1152,5376,256,2304,1152,576,576};
constexpr int CV_F[18]  = {0,0,0,0,0,0,0,0,  64,64,128,256,256,5376,128,64,64,3};

constexpr u64 cv_elems(int i) { return (u64)CV_R[i] * CV_NP[i]; }
constexpr u64 cv_off(int i) { u64 o = 0; for (int j = 0; j < i; ++j) o += (cv_elems(j) + 255) & ~(u64)255; return o; }
constexpr int cv_blk(int i) { return (int)((cv_elems(i) + 255) >> 8); }
constexpr int cv_start(int i) { int s = 0; for (int j = 0; j < i; ++j) s += cv_blk(j); return s; }

__global__ __launch_bounds__(256) void cvt_all(CvtPtrs ps, _Float16* __restrict__ dst)
{
    const int bx = blockIdx.x, t = threadIdx.x;
    #pragma unroll
    for (int i = 0; i < 18; ++i) {
        if (bx >= cv_start(i) && bx < cv_start(i + 1)) {
            const u64 e = (u64)(bx - cv_start(i)) * 256 + t;
            if (e < cv_elems(i)) {
                const int NP = CV_NP[i], N = CV_N[i], Fo = CV_F[i];
                int row = (int)(e / (u64)NP);
                int col = (int)(e - (u64)row * NP);
                float v = 0.f;
                const float* s = ps.p[i];
                if (Fo == 0) { if (col < N) v = s[(u64)row * N + col]; }
                else         { if (col < N && row < Fo) v = s[(u64)col * Fo + row]; }
                dst[cv_off(i) + e] = (_Float16)v;
            }
        }
    }
}

__global__ void cvt_x(const float* __restrict__ src, _Float16* __restrict__ dst)
{
    int i = blockIdx.x * 256 + threadIdx.x;
    if (i >= 64 * 5024 * 3) return;
    int v = i / 192;
    int r = i - v * 192;
    int b = r / 3, c = r - b * 3;
    dst[i] = (_Float16)src[((u64)b * 5024 + v) * 3 + c];
}

__global__ void reduce_fce(const float* __restrict__ part, const float* __restrict__ bias,
                           _Float16* __restrict__ z)
{
    int i = blockIdx.x * 256 + threadIdx.x;  // 64*256
    int fl = i & 255;
    float s = bias[fl];
    #pragma unroll
    for (int p = 0; p < 8; ++p) s += part[(u64)p * 16384 + i];
    z[i] = (_Float16)s;
}

extern "C" void kernel_launch(void* const* d_in, const int* in_sizes, int n_in,
                              void* d_out, int out_size, void* d_ws, size_t ws_size,
                              hipStream_t stream)
{
    const float* x  = (const float*)d_in[0];
    const int* s0 = (const int*)d_in[1];
    const int* s1 = (const int*)d_in[2];
    const int* s2 = (const int*)d_in[3];
    const int* s3 = (const int*)d_in[4];
    const float* be0 = (const float*)d_in[14];
    const float* be1 = (const float*)d_in[16];
    const float* be2 = (const float*)d_in[18];
    const float* be3 = (const float*)d_in[20];
    const float* fceb = (const float*)d_in[22];
    const float* fcdb = (const float*)d_in[24];
    const float* bd0 = (const float*)d_in[26];
    const float* bd1 = (const float*)d_in[28];
    const float* bd2 = (const float*)d_in[30];
    const float* bd3 = (const float*)d_in[32];

    _Float16* W = (_Float16*)d_ws;
    size_t off = 0;
    auto alloc = [&](size_t e) { size_t o = off; off += (e + 255) & ~(size_t)255; return o; };

    const size_t oActV = alloc((size_t)5024 * 4096);   // [vertex][(b,f)]
    const size_t oActT = alloc((size_t)4096 * 5120);   // [(b,f)][vertex_padded]
    const size_t oZ    = alloc((size_t)64 * 256);
    const size_t oPart = alloc((size_t)8 * 64 * 256 * 2);   // fp32 partials (fce)
    const size_t oU3in = alloc((size_t)16384 * 32);
    const size_t oXp   = alloc((size_t)5024 * 192);
    const size_t oCvt  = alloc((size_t)(cv_off(17) + ((cv_elems(17) + 255) & ~(u64)255)));
    auto wofs = [&](int i) { return oCvt + (size_t)cv_off(i); };

    // ---- conversions ----
    cvt_x<<<dim3((64 * 5024 * 3 + 255) / 256), 256, 0, stream>>>(x, W + oXp);
    {
        CvtPtrs ps;
        ps.p[0] = (const float*)d_in[5];   // D0
        ps.p[1] = (const float*)d_in[6];   // U0
        ps.p[2] = (const float*)d_in[7];   // D1
        ps.p[3] = (const float*)d_in[8];   // U1
        ps.p[4] = (const float*)d_in[9];   // D2
        ps.p[5] = (const float*)d_in[10];  // U2
        ps.p[6] = (const float*)d_in[11];  // D3
        ps.p[7] = (const float*)d_in[12];  // U3
        ps.p[8] = (const float*)d_in[13];  // We0
        ps.p[9] = (const float*)d_in[15];  // We1
        ps.p[10] = (const float*)d_in[17]; // We2
        ps.p[11] = (const float*)d_in[19]; // We3
        ps.p[12] = (const float*)d_in[21]; // fceW
        ps.p[13] = (const float*)d_in[23]; // fcdW
        ps.p[14] = (const float*)d_in[25]; // Wd0
        ps.p[15] = (const float*)d_in[27]; // Wd1
        ps.p[16] = (const float*)d_in[29]; // Wd2
        ps.p[17] = (const float*)d_in[31]; // Wd3
        cvt_all<<<dim3(cv_start(18)), 256, 0, stream>>>(ps, W + oCvt);
    }
    hipMemsetAsync(W + oU3in, 0, (size_t)16384 * 32 * sizeof(_Float16), stream);

    #define GEMM(AM, EP, BM_, BF_, WM_, WF_, gx, gy, gz, Aw_, ars_, idx_, FiL_, Bw_, bias_, Cp_, crs_, Mp_, M_, Np_, F_, fl_, ksp_) \
        gemm_k<AM, EP, BM_, BF_, WM_, WF_><<<dim3(gx, gy, gz), 256, 0, stream>>>( \
            Aw_, ars_, idx_, FiL_, Bw_, bias_, Cp_, crs_, Mp_, M_, Np_, F_, fl_, ksp_)
    #define POOL(TBM_, gx, gy, Aw_, Bw_, Cp_, M_, Np_, crs_) \
        pool2_k<TBM_><<<dim3(gx, gy), 256, 0, stream>>>(Aw_, Bw_, Cp_, M_, Np_, crs_)
    #define POOL4(gx, gy, Aw_, Bw_, Cp_, M_, Np_, crs_) \
        pool4_k<<<dim3(gx, gy), 256, 0, stream>>>(Aw_, Bw_, Cp_, M_, Np_, crs_)

    // ---- encoder ----
    GEMM(2, EPI_TR, 128, 64, 2, 2, 1, 40, 64, W + oXp, 192, s0, 0,
         W + wofs(8), be0, W + oActT, (u64)64 * 5120, 5120, 5024, 32, 64, 3, 0);
    POOL4(32, 20, W + wofs(0), W + oActT, W + oActV, 1257, 5120, 4096);
    GEMM(1, EPI_TR, 128, 64, 2, 2, 1, 10, 64, W + oActV, 4096, s1, 6,
         W + wofs(9), be1, W + oActT, (u64)64 * 1280, 1280, 1257, 576, 64, 3, 0);
    POOL(64, 32, 5, W + wofs(2), W + oActT, W + oActV, 315, 1280, 4096);
    GEMM(1, EPI_TR, 128, 64, 2, 2, 2, 3, 64, W + oActV, 4096, s2, 6,
         W + wofs(10), be2, W + oActT, (u64)128 * 320, 320, 315, 576, 128, 3, 0);
    POOL(64, 64, 2, W + wofs(4), W + oActT, W + oActV, 80, 320, 8192);
    GEMM(1, EPI_TR, 128, 64, 2, 2, 4, 1, 64, W + oActV, 8192, s3, 7,
         W + wofs(11), be3, W + oActT, (u64)256 * 96, 96, 80, 1152, 256, 3, 0);
    POOL(64, 128, 1, W + wofs(6), W + oActT, W + oActV, 21, 96, 16384);
    // ---- bottleneck ----
    GEMM(4, EPI_PART, 64, 64, 2, 2, 4, 1, 8, W + oActV, 16384, nullptr, 8,
         W + wofs(12), nullptr, W + oPart, (u64)64 * 256, 0, 64, 5376, 256, 0, 21);
    reduce_fce<<<dim3(64), 256, 0, stream>>>((const float*)(W + oPart), fceb, W + oZ);
    GEMM(3, EPI_FCD, 64, 128, 2, 2, 42, 1, 1, W + oZ, 0, nullptr, 0,
         W + wofs(13), fcdb, W + oU3in, 0, 0, 64, 256, 5376, 0, 0);
    // ---- decoder ----
    POOL(64, 128, 2, W + wofs(7), W + oU3in, W + oActV, 80, 32, 16384);
    GEMM(1, EPI_TR, 128, 64, 2, 2, 2, 1, 64, W + oActV, 16384, s3, 8,
         W + wofs(14), bd0, W + oActT, (u64)128 * 96, 96, 80, 2304, 128, 3, 0);
    POOL(64, 64, 5, W + wofs(5), W + oActT, W + oActV, 315, 96, 8192);
    GEMM(1, EPI_TR, 128, 64, 2, 2, 1, 3, 64, W + oActV, 8192, s2, 7,
         W + wofs(15), bd1, W + oActT, (u64)64 * 320, 320, 315, 1152, 64, 3, 0);
    POOL4(32, 20, W + wofs(3), W + oActT, W + oActV, 1257, 320, 4096);
    GEMM(1, EPI_TR, 128, 64, 2, 2, 1, 10, 64, W + oActV, 4096, s1, 6,
         W + wofs(16), bd2, W + oActT, (u64)64 * 1280, 1280, 1257, 576, 64, 3, 0);
    POOL4(32, 79, W + wofs(1), W + oActT, W + oActV, 5024, 1280, 4096);
    GEMM(5, EPI_OUT, 128, 16, 4, 1, 1, 2512, 1, W + oActV, 4096, s0, 6,
         W + wofs(17), bd3, d_out, 0, 5024, 321536, 576, 3, 2, 0);
    #undef GEMM
    #undef POOL
    #undef POOL4
}

// Round 17
// 505.826 us; speedup vs baseline: 1.5392x; 1.0928x over previous
//
#include <hip/hip_runtime.h>
#include <math.h>

typedef __attribute__((ext_vector_type(8))) _Float16 half8;
typedef __attribute__((ext_vector_type(4))) _Float16 half4;
typedef __attribute__((ext_vector_type(4))) float f32x4;
typedef unsigned long long u64;

#define BK 32

#define EPI_NAT  0
#define EPI_TR   1
#define EPI_FCD  2
#define EPI_OUT  3
#define EPI_PART 4

typedef const __attribute__((address_space(1))) void* gas1;
typedef __attribute__((address_space(3))) void* las3;

__device__ __forceinline__ void gl16(const void* g, void* l) {
    __builtin_amdgcn_global_load_lds((gas1)g, (las3)l, 16, 0, 0);
}
template<int N> __device__ __forceinline__ void vwait() {
    asm volatile("s_waitcnt vmcnt(%0)" :: "n"(N) : "memory");
}
__device__ __forceinline__ void barx() {
    asm volatile("" ::: "memory");
    __builtin_amdgcn_s_barrier();
    asm volatile("" ::: "memory");
}

// ============ pool4: 256 thr, 4 waves (2x2), 64x128 tile, BK=64, 2-buf (r16 WIN) ============
__global__ __launch_bounds__(256, 3) void pool4_k(
    const _Float16* __restrict__ Aw, const _Float16* __restrict__ Bw,
    _Float16* __restrict__ Cp, int M, int Np, u64 c_rs)
{
    constexpr int LPS = 6;

    __shared__ _Float16 sA[2][64][64];
    __shared__ _Float16 sB[2][128][64];

    const int t  = threadIdx.x;
    const int m0 = blockIdx.y * 64;
    const int f0 = blockIdx.x * 128;
    const int lane = t & 63;
    const int wid  = t >> 6;
    const int wm = wid >> 1;
    const int wf = wid & 1;
    const int lm = lane & 15;
    const int lg = lane >> 4;

    f32x4 acc[2][4];
    #pragma unroll
    for (int i = 0; i < 2; ++i)
        #pragma unroll
        for (int j = 0; j < 4; ++j)
            acc[i][j] = (f32x4)0.0f;

    auto stage = [&](int buf, int ks) {
        #pragma unroll
        for (int j = 0; j < 2; ++j) {
            int c   = t + j * 256;
            int row = c >> 3;
            int ch  = (c & 7) ^ (row & 7);
            int rc  = m0 + row; if (rc >= M) rc = M - 1;
            gl16(Aw + (u64)rc * Np + ks * 64 + ch * 8,
                 (_Float16*)&sA[buf][0][0] + (u64)c * 8);
        }
        #pragma unroll
        for (int j = 0; j < 4; ++j) {
            int c   = t + j * 256;
            int row = c >> 3;
            int ch  = (c & 7) ^ (row & 7);
            gl16(Bw + (u64)(f0 + row) * Np + ks * 64 + ch * 8,
                 (_Float16*)&sB[buf][0][0] + (u64)c * 8);
        }
    };

    auto compute = [&](int buf) {
        #pragma unroll
        for (int kh = 0; kh < 2; ++kh) {
            const int ch = (kh * 4 + lg) ^ (lm & 7);
            half8 af[2], bf[4];
            #pragma unroll
            for (int i = 0; i < 2; ++i)
                af[i] = *(const half8*)&sA[buf][wm * 32 + i * 16 + lm][ch * 8];
            #pragma unroll
            for (int j = 0; j < 4; ++j)
                bf[j] = *(const half8*)&sB[buf][wf * 64 + j * 16 + lm][ch * 8];
            #pragma unroll
            for (int i = 0; i < 2; ++i)
                #pragma unroll
                for (int j = 0; j < 4; ++j)
                    acc[i][j] = __builtin_amdgcn_mfma_f32_16x16x32_f16(af[i], bf[j], acc[i][j], 0, 0, 0);
        }
    };

    const int ke = Np / 64;
    stage(0, 0);
    if (1 < ke) stage(1, 1);
    for (int ks = 0; ks < ke; ++ks) {
        if (ke - ks >= 2) vwait<LPS>();
        else              vwait<0>();
        barx();
        compute(ks & 1);
        barx();
        if (ks + 2 < ke) stage(ks & 1, ks + 2);
    }

    #pragma unroll
    for (int j = 0; j < 4; ++j) {
        int fl = f0 + wf * 64 + j * 16 + lm;
        #pragma unroll
        for (int i = 0; i < 2; ++i) {
            #pragma unroll
            for (int r = 0; r < 4; ++r) {
                int m = m0 + wm * 32 + i * 16 + lg * 4 + r;
                if (m < M)
                    Cp[(u64)m * c_rs + fl] = (_Float16)acc[i][j][r];
            }
        }
    }
}

// ============ pool2 (r9 optimum): 256 thr, 4 waves (2x2), TBMx128, BK=32, 3-buf ============
template<int TBM>
__global__ __launch_bounds__(256, 3) void pool2_k(
    const _Float16* __restrict__ Aw, const _Float16* __restrict__ Bw,
    _Float16* __restrict__ Cp, int M, int Np, u64 c_rs)
{
    constexpr int FM  = TBM / 32;
    constexpr int LPS = TBM / 64 + 2;

    __shared__ _Float16 sA[3][TBM][BK];
    __shared__ _Float16 sB[3][128][BK];

    const int t  = threadIdx.x;
    const int m0 = blockIdx.y * TBM;
    const int f0 = blockIdx.x * 128;
    const int lane = t & 63;
    const int wid  = t >> 6;
    const int wm = wid >> 1;
    const int wf = wid & 1;
    const int lm = lane & 15;
    const int lg = lane >> 4;

    f32x4 acc[FM][4];
    #pragma unroll
    for (int i = 0; i < FM; ++i)
        #pragma unroll
        for (int j = 0; j < 4; ++j)
            acc[i][j] = (f32x4)0.0f;

    auto stage = [&](int buf, int ks) {
        #pragma unroll
        for (int j = 0; j < TBM / 64; ++j) {
            int c   = t + j * 256;
            int row = c >> 2;
            int sw  = ((c & 3) ^ ((row >> 1) & 3)) * 8;
            int rc  = m0 + row; if (rc >= M) rc = M - 1;
            gl16(Aw + (u64)rc * Np + ks * BK + sw,
                 (_Float16*)&sA[buf][0][0] + (u64)c * 8);
        }
        #pragma unroll
        for (int j = 0; j < 2; ++j) {
            int c   = t + j * 256;
            int row = c >> 2;
            int sw  = ((c & 3) ^ ((row >> 1) & 3)) * 8;
            gl16(Bw + (u64)(f0 + row) * Np + ks * BK + sw,
                 (_Float16*)&sB[buf][0][0] + (u64)c * 8);
        }
    };

    auto compute = [&](int buf) {
        const int sa = (lg ^ ((lm >> 1) & 3)) * 8;
        half8 af[FM], bf[4];
        #pragma unroll
        for (int i = 0; i < FM; ++i)
            af[i] = *(const half8*)&sA[buf][wm * (FM * 16) + i * 16 + lm][sa];
        #pragma unroll
        for (int j = 0; j < 4; ++j)
            bf[j] = *(const half8*)&sB[buf][wf * 64 + j * 16 + lm][sa];
        #pragma unroll
        for (int i = 0; i < FM; ++i)
            #pragma unroll
            for (int j = 0; j < 4; ++j)
                acc[i][j] = __builtin_amdgcn_mfma_f32_16x16x32_f16(af[i], bf[j], acc[i][j], 0, 0, 0);
    };

    const int ke = Np / BK;
    stage(0, 0);
    if (1 < ke) stage(1, 1);
    if (2 < ke) stage(2, 2);
    int cur = 0;
    for (int ks = 0; ks < ke; ++ks) {
        int rem = ke - ks;
        if (rem >= 3)      vwait<2 * LPS>();
        else if (rem == 2) vwait<LPS>();
        else               vwait<0>();
        barx();
        compute(cur);
        barx();
        if (ks + 3 < ke) stage(cur, ks + 3);
        cur = (cur == 2) ? 0 : cur + 1;
    }

    #pragma unroll
    for (int j = 0; j < 4; ++j) {
        int fl = f0 + wf * 64 + j * 16 + lm;
        #pragma unroll
        for (int i = 0; i < FM; ++i) {
            #pragma unroll
            for (int r = 0; r < 4; ++r) {
                int m = m0 + wm * (FM * 16) + i * 16 + lg * 4 + r;
                if (m < M)
                    Cp[(u64)m * c_rs + fl] = (_Float16)acc[i][j][r];
            }
        }
    }
}

// ============ general kernel (sconv / fc) ============
// AMODE: 1 sconv gather (idx via LDS), 2 sconv0 (vectorized half4 gather, Xp4, K=64),
//        3 fc, 4 fc-enc split-K, 5 sconv rows-folded [Wd3]
template<int AMODE, int EPI, int TBM, int TBF, int WM, int WF>
__global__ __launch_bounds__(256) void gemm_k(
    const _Float16* __restrict__ Aw, u64 a_rs,
    const int* __restrict__ idx, int FiLog,
    const _Float16* __restrict__ Bw,
    const float* __restrict__ bias,
    void* __restrict__ Cp, u64 c_rs, int Mp_out,
    int M, int Np, int F, int flags, int ksp)   // flags: bit0 ELU, bit1 zeroLast
{
    constexpr int FM = TBM / WM / 16;
    constexpr int FF = TBF / WF / 16;
    constexpr int LPS_A = TBM / 64;
    constexpr bool BSM = (TBF < 64);
    constexpr int LPS_B = BSM ? 0 : TBF / 64;
    constexpr int LW0 = LPS_A + (BSM ? 1 : LPS_B);
    constexpr int LWX = LPS_A + LPS_B;
    constexpr int NI = (AMODE == 1 || AMODE == 2) ? TBM : 2;

    __shared__ _Float16 sA[3][TBM][BK];
    __shared__ _Float16 sB[3][TBF][BK];
    __shared__ int sIdx[NI][9];

    const int t  = threadIdx.x;
    const int b  = blockIdx.z;
    const int m0 = blockIdx.y * TBM;
    const int f0 = blockIdx.x * TBF;
    const int lane = t & 63;
    const int wid  = t >> 6;
    const int wm = wid / WF;
    const int wf = wid % WF;
    const int lm = lane & 15;
    const int lg = lane >> 4;
    const int Fi = 1 << FiLog;

    f32x4 acc[FM][FF];
    #pragma unroll
    for (int i = 0; i < FM; ++i)
        #pragma unroll
        for (int j = 0; j < FF; ++j)
            acc[i][j] = (f32x4)0.0f;

    if constexpr (AMODE == 1 || AMODE == 2) {
        for (int i = t; i < TBM * 9; i += 256) {
            int r = i / 9, k = i - r * 9;
            int rc = m0 + r; if (rc >= M) rc = M - 1;
            sIdx[r][k] = idx[rc * 9 + k];
        }
        __syncthreads();
    } else if constexpr (AMODE == 5) {
        if (t < 18) {
            int r = t / 9, k = t - r * 9;
            sIdx[r][k] = idx[((m0 >> 6) + r) * 9 + k];
        }
        __syncthreads();
    }

    auto stage = [&](int buf, int ks) {
        if constexpr (AMODE != 2) {
            #pragma unroll
            for (int j = 0; j < LPS_A; ++j) {
                int c   = t + j * 256;
                int row = c >> 2;
                int sw  = ((c & 3) ^ ((row >> 1) & 3)) * 8;
                int col = ks * BK + sw;
                const _Float16* src;
                if constexpr (AMODE == 3) {
                    int rc = m0 + row; if (rc >= M) rc = M - 1;
                    src = Aw + (u64)rc * Np + col;
                } else if constexpr (AMODE == 1) {
                    int k = col >> FiLog, fi = col & (Fi - 1);
                    src = Aw + (u64)sIdx[row][k] * a_rs + b * Fi + fi;
                } else if constexpr (AMODE == 4) {
                    int k = col >> FiLog, fi = col & (Fi - 1);
                    src = Aw + (u64)k * a_rs + (m0 + row) * Fi + fi;
                } else {  // 5
                    int k = col >> FiLog, fi = col & (Fi - 1);
                    int bb = (m0 + row) & 63;
                    src = Aw + (u64)sIdx[row >> 6][k] * a_rs + bb * Fi + fi;
                }
                gl16(src, &sA[buf][row][(c & 3) * 8]);
            }
        }
        if constexpr (!BSM) {
            #pragma unroll
            for (int j = 0; j < LPS_B; ++j) {
                int c   = t + j * 256;
                int row = c >> 2;
                int sw  = ((c & 3) ^ ((row >> 1) & 3)) * 8;
                gl16(Bw + (u64)(f0 + row) * Np + ks * BK + sw, &sB[buf][row][(c & 3) * 8]);
            }
        } else {
            if (wid == 0) {
                int c   = t;
                int row = c >> 2;
                int sw  = ((c & 3) ^ ((row >> 1) & 3)) * 8;
                gl16(Bw + (u64)(f0 + row) * Np + ks * BK + sw, &sB[buf][row][(c & 3) * 8]);
            }
        }
    };

    auto compute = [&](int buf) {
        const int sa = (lg ^ ((lm >> 1) & 3)) * 8;
        half8 af[FM], bf[FF];
        #pragma unroll
        for (int i = 0; i < FM; ++i)
            af[i] = *(const half8*)&sA[buf][wm * (FM * 16) + i * 16 + lm][sa];
        #pragma unroll
        for (int j = 0; j < FF; ++j)
            bf[j] = *(const half8*)&sB[buf][wf * (FF * 16) + j * 16 + lm][sa];
        #pragma unroll
        for (int i = 0; i < FM; ++i)
            #pragma unroll
            for (int j = 0; j < FF; ++j)
                acc[i][j] = __builtin_amdgcn_mfma_f32_16x16x32_f16(af[i], bf[j], acc[i][j], 0, 0, 0);
    };

    if constexpr (AMODE == 2) {
        // B: two K-steps via gl16 (Np = 64); A: vectorized half4 gather into bufs 0/1
        stage(0, 0);
        stage(1, 1);
        {
            int row = t >> 1;
            int h   = t & 1;          // which K-half / buf
            #pragma unroll
            for (int cc = 0; cc < 4; ++cc) {
                int g0 = h * 8 + cc * 2;
                int g1 = g0 + 1;
                half4 lo = {(_Float16)0,(_Float16)0,(_Float16)0,(_Float16)0};
                half4 hi = lo;
                if (g0 < 9) lo = *(const half4*)(Aw + (u64)sIdx[row][g0] * a_rs + b * 4);
                if (g1 < 9) hi = *(const half4*)(Aw + (u64)sIdx[row][g1] * a_rs + b * 4);
                half8 w;
                #pragma unroll
                for (int q = 0; q < 4; ++q) { w[q] = lo[q]; w[4 + q] = hi[q]; }
                int cp = cc ^ ((row >> 1) & 3);
                *(half8*)&sA[h][row][cp * 8] = w;
            }
        }
        vwait<0>();
        __syncthreads();
        compute(0);
        compute(1);
    } else {
        int kb = 0, ke = Np / BK;
        if constexpr (AMODE == 4) { kb = b * ksp; ke = kb + ksp; }
        stage(0, kb);
        if (kb + 1 < ke) stage(1, kb + 1);
        if (kb + 2 < ke) stage(2, kb + 2);
        int cur = 0;
        for (int ks = kb; ks < ke; ++ks) {
            int rem = ke - ks;
            if (rem >= 3) {
                if constexpr (LW0 == LWX) vwait<2 * LW0>();
                else { if (wid == 0) vwait<2 * LW0>(); else vwait<2 * LWX>(); }
            } else if (rem == 2) {
                if constexpr (LW0 == LWX) vwait<LW0>();
                else { if (wid == 0) vwait<LW0>(); else vwait<LWX>(); }
            } else {
                vwait<0>();
            }
            barx();
            compute(cur);
            barx();
            if (ks + 3 < ke) stage(cur, ks + 3);
            cur = (cur == 2) ? 0 : cur + 1;
        }
    }

    // ---- epilogue ----
    if constexpr (EPI == EPI_TR) {
        // packed half4 stores: 4 consecutive m per (i,j) at fixed fl
        #pragma unroll
        for (int j = 0; j < FF; ++j) {
            int fl = f0 + wf * (FF * 16) + j * 16 + lm;
            float bv = (bias != nullptr && fl < F) ? bias[fl] : 0.f;
            #pragma unroll
            for (int i = 0; i < FM; ++i) {
                int mb = m0 + wm * (FM * 16) + i * 16 + lg * 4;
                if (fl < F && mb < Mp_out) {
                    half4 o;
                    #pragma unroll
                    for (int r = 0; r < 4; ++r) {
                        int m = mb + r;
                        float v = acc[i][j][r] + bv;
                        if (flags & 1) v = (v > 0.f) ? v : expm1f(v);
                        o[r] = (m < M && !((flags & 2) && m == M - 1)) ? (_Float16)v : (_Float16)0.f;
                    }
                    *(half4*)&((_Float16*)Cp)[(u64)b * c_rs + (u64)fl * Mp_out + mb] = o;
                }
            }
        }
    } else {
        #pragma unroll
        for (int j = 0; j < FF; ++j) {
            int fl = f0 + wf * (FF * 16) + j * 16 + lm;
            float bv = 0.f;
            if (bias != nullptr && fl < F) bv = bias[fl];
            #pragma unroll
            for (int i = 0; i < FM; ++i) {
                #pragma unroll
                for (int r = 0; r < 4; ++r) {
                    int m = m0 + wm * (FM * 16) + i * 16 + lg * 4 + r;
                    float v = acc[i][j][r] + bv;
                    if (flags & 1) v = (v > 0.f) ? v : expm1f(v);
                    if constexpr (EPI == EPI_NAT) {
                        if (m < M && fl < F)
                            ((_Float16*)Cp)[(u64)m * c_rs + fl] = (_Float16)v;
                    } else if constexpr (EPI == EPI_FCD) {
                        if (m < M && fl < F)
                            ((_Float16*)Cp)[((u64)m * 256 + (fl & 255)) * 32 + (fl >> 8)] = (_Float16)v;
                    } else if constexpr (EPI == EPI_PART) {
                        if (m < M && fl < F)
                            ((float*)Cp)[(u64)b * c_rs + (u64)m * F + fl] = v;
                    } else {  // EPI_OUT (rows folded: m = v*64+b)
                        if (m < M && fl < F) {
                            int vo = m >> 6, bb = m & 63;
                            float o = ((flags & 2) && vo == Mp_out - 1) ? 0.f : v;
                            ((float*)Cp)[((u64)bb * Mp_out + vo) * 3 + fl] = o;
                        }
                    }
                }
            }
        }
    }
}

// ---- fused weight conversion ----
struct CvtPtrs { const float* p[18]; };

constexpr int CV_R[18]  = {1257,5024,315,1257,80,315,21,80,  64,64,128,256,256,5376,128,64,64,16};
constexpr int CV_N[18]  = {5024,1257,1257,315,315,80,80,21,  27,576,576,1152,5376,256,2304,1152,576,576};
constexpr int CV_NP[18] = {5120,1280,1280,320,320,96,96,32,  64,576,576,1152,5376,256,2304,1152,576,576};
constexpr int CV_F[18]  = {0,0,0,0,0,0,0,0,  64,64,128,256,256,5376,128,64,64,3};

constexpr u64 cv_elems(int i) { return (u64)CV_R[i] * CV_NP[i]; }
constexpr u64 cv_off(int i) { u64 o = 0; for (int j = 0; j < i; ++j) o += (cv_elems(j) + 255) & ~(u64)255; return o; }
constexpr int cv_blk(int i) { return (int)((cv_elems(i) + 255) >> 8); }
constexpr int cv_start(int i) { int s = 0; for (int j = 0; j < i; ++j) s += cv_blk(j); return s; }

__global__ __launch_bounds__(256) void cvt_all(CvtPtrs ps, _Float16* __restrict__ dst)
{
    const int bx = blockIdx.x, t = threadIdx.x;
    #pragma unroll
    for (int i = 0; i < 18; ++i) {
        if (bx >= cv_start(i) && bx < cv_start(i + 1)) {
            const u64 e = (u64)(bx - cv_start(i)) * 256 + t;
            if (e < cv_elems(i)) {
                const int NP = CV_NP[i], N = CV_N[i], Fo = CV_F[i];
                int row = (int)(e / (u64)NP);
                int col = (int)(e - (u64)row * NP);
                float v = 0.f;
                const float* s = ps.p[i];
                if (i == 8) {
                    // We0 padded: col -> (k = col>>2, c = col&3); real iff c<3 && k<9
                    int k = col >> 2, c = col & 3;
                    if (c < 3 && k < 9) v = s[(u64)(k * 3 + c) * Fo + row];
                } else if (Fo == 0) {
                    if (col < N) v = s[(u64)row * N + col];
                } else {
                    if (col < N && row < Fo) v = s[(u64)col * Fo + row];
                }
                dst[cv_off(i) + e] = (_Float16)v;
            }
        }
    }
}

__global__ void cvt_x(const float* __restrict__ src, _Float16* __restrict__ dst)
{
    // Xp4 layout: [v][b][4], 4th element zero
    int i = blockIdx.x * 256 + threadIdx.x;
    if (i >= 5024 * 256) return;
    int v = i >> 8;
    int r = i & 255;
    int b = r >> 2, c = r & 3;
    dst[i] = (c < 3) ? (_Float16)src[((u64)b * 5024 + v) * 3 + c] : (_Float16)0.f;
}

__global__ void reduce_fce(const float* __restrict__ part, const float* __restrict__ bias,
                           _Float16* __restrict__ z)
{
    int i = blockIdx.x * 256 + threadIdx.x;  // 64*256
    int fl = i & 255;
    float s = bias[fl];
    #pragma unroll
    for (int p = 0; p < 8; ++p) s += part[(u64)p * 16384 + i];
    z[i] = (_Float16)s;
}

extern "C" void kernel_launch(void* const* d_in, const int* in_sizes, int n_in,
                              void* d_out, int out_size, void* d_ws, size_t ws_size,
                              hipStream_t stream)
{
    const float* x  = (const float*)d_in[0];
    const int* s0 = (const int*)d_in[1];
    const int* s1 = (const int*)d_in[2];
    const int* s2 = (const int*)d_in[3];
    const int* s3 = (const int*)d_in[4];
    const float* be0 = (const float*)d_in[14];
    const float* be1 = (const float*)d_in[16];
    const float* be2 = (const float*)d_in[18];
    const float* be3 = (const float*)d_in[20];
    const float* fceb = (const float*)d_in[22];
    const float* fcdb = (const float*)d_in[24];
    const float* bd0 = (const float*)d_in[26];
    const float* bd1 = (const float*)d_in[28];
    const float* bd2 = (const float*)d_in[30];
    const float* bd3 = (const float*)d_in[32];

    _Float16* W = (_Float16*)d_ws;
    size_t off = 0;
    auto alloc = [&](size_t e) { size_t o = off; off += (e + 255) & ~(size_t)255; return o; };

    const size_t oActV = alloc((size_t)5024 * 4096);   // [vertex][(b,f)]
    const size_t oActT = alloc((size_t)4096 * 5120);   // [(b,f)][vertex_padded]
    const size_t oZ    = alloc((size_t)64 * 256);
    const size_t oPart = alloc((size_t)8 * 64 * 256 * 2);   // fp32 partials (fce)
    const size_t oU3in = alloc((size_t)16384 * 32);
    const size_t oXp   = alloc((size_t)5024 * 256);    // Xp4 [v][b][4]
    const size_t oCvt  = alloc((size_t)(cv_off(17) + ((cv_elems(17) + 255) & ~(u64)255)));
    auto wofs = [&](int i) { return oCvt + (size_t)cv_off(i); };

    // ---- conversions ----
    cvt_x<<<dim3(5024), 256, 0, stream>>>(x, W + oXp);
    {
        CvtPtrs ps;
        ps.p[0] = (const float*)d_in[5];   // D0
        ps.p[1] = (const float*)d_in[6];   // U0
        ps.p[2] = (const float*)d_in[7];   // D1
        ps.p[3] = (const float*)d_in[8];   // U1
        ps.p[4] = (const float*)d_in[9];   // D2
        ps.p[5] = (const float*)d_in[10];  // U2
        ps.p[6] = (const float*)d_in[11];  // D3
        ps.p[7] = (const float*)d_in[12];  // U3
        ps.p[8] = (const float*)d_in[13];  // We0
        ps.p[9] = (const float*)d_in[15];  // We1
        ps.p[10] = (const float*)d_in[17]; // We2
        ps.p[11] = (const float*)d_in[19]; // We3
        ps.p[12] = (const float*)d_in[21]; // fceW
        ps.p[13] = (const float*)d_in[23]; // fcdW
        ps.p[14] = (const float*)d_in[25]; // Wd0
        ps.p[15] = (const float*)d_in[27]; // Wd1
        ps.p[16] = (const float*)d_in[29]; // Wd2
        ps.p[17] = (const float*)d_in[31]; // Wd3
        cvt_all<<<dim3(cv_start(18)), 256, 0, stream>>>(ps, W + oCvt);
    }
    hipMemsetAsync(W + oU3in, 0, (size_t)16384 * 32 * sizeof(_Float16), stream);

    #define GEMM(AM, EP, BM_, BF_, WM_, WF_, gx, gy, gz, Aw_, ars_, idx_, FiL_, Bw_, bias_, Cp_, crs_, Mp_, M_, Np_, F_, fl_, ksp_) \
        gemm_k<AM, EP, BM_, BF_, WM_, WF_><<<dim3(gx, gy, gz), 256, 0, stream>>>( \
            Aw_, ars_, idx_, FiL_, Bw_, bias_, Cp_, crs_, Mp_, M_, Np_, F_, fl_, ksp_)
    #define POOL(TBM_, gx, gy, Aw_, Bw_, Cp_, M_, Np_, crs_) \
        pool2_k<TBM_><<<dim3(gx, gy), 256, 0, stream>>>(Aw_, Bw_, Cp_, M_, Np_, crs_)
    #define POOL4(gx, gy, Aw_, Bw_, Cp_, M_, Np_, crs_) \
        pool4_k<<<dim3(gx, gy), 256, 0, stream>>>(Aw_, Bw_, Cp_, M_, Np_, crs_)

    // ---- encoder ----
    GEMM(2, EPI_TR, 128, 64, 2, 2, 1, 40, 64, W + oXp, 256, s0, 0,
         W + wofs(8), be0, W + oActT, (u64)64 * 5120, 5120, 5024, 64, 64, 3, 0);
    POOL4(32, 20, W + wofs(0), W + oActT, W + oActV, 1257, 5120, 4096);
    GEMM(1, EPI_TR, 128, 64, 2, 2, 1, 10, 64, W + oActV, 4096, s1, 6,
         W + wofs(9), be1, W + oActT, (u64)64 * 1280, 1280, 1257, 576, 64, 3, 0);
    POOL(64, 32, 5, W + wofs(2), W + oActT, W + oActV, 315, 1280, 4096);
    GEMM(1, EPI_TR, 128, 64, 2, 2, 2, 3, 64, W + oActV, 4096, s2, 6,
         W + wofs(10), be2, W + oActT, (u64)128 * 320, 320, 315, 576, 128, 3, 0);
    POOL(64, 64, 2, W + wofs(4), W + oActT, W + oActV, 80, 320, 8192);
    GEMM(1, EPI_TR, 128, 64, 2, 2, 4, 1, 64, W + oActV, 8192, s3, 7,
         W + wofs(11), be3, W + oActT, (u64)256 * 96, 96, 80, 1152, 256, 3, 0);
    POOL(64, 128, 1, W + wofs(6), W + oActT, W + oActV, 21, 96, 16384);
    // ---- bottleneck ----
    GEMM(4, EPI_PART, 64, 64, 2, 2, 4, 1, 8, W + oActV, 16384, nullptr, 8,
         W + wofs(12), nullptr, W + oPart, (u64)64 * 256, 0, 64, 5376, 256, 0, 21);
    reduce_fce<<<dim3(64), 256, 0, stream>>>((const float*)(W + oPart), fceb, W + oZ);
    GEMM(3, EPI_FCD, 64, 128, 2, 2, 42, 1, 1, W + oZ, 0, nullptr, 0,
         W + wofs(13), fcdb, W + oU3in, 0, 0, 64, 256, 5376, 0, 0);
    // ---- decoder ----
    POOL(64, 128, 2, W + wofs(7), W + oU3in, W + oActV, 80, 32, 16384);
    GEMM(1, EPI_TR, 128, 64, 2, 2, 2, 1, 64, W + oActV, 16384, s3, 8,
         W + wofs(14), bd0, W + oActT, (u64)128 * 96, 96, 80, 2304, 128, 3, 0);
    POOL(64, 64, 5, W + wofs(5), W + oActT, W + oActV, 315, 96, 8192);
    GEMM(1, EPI_TR, 128, 64, 2, 2, 1, 3, 64, W + oActV, 8192, s2, 7,
         W + wofs(15), bd1, W + oActT, (u64)64 * 320, 320, 315, 1152, 64, 3, 0);
    POOL4(32, 20, W + wofs(3), W + oActT, W + oActV, 1257, 320, 4096);
    GEMM(1, EPI_TR, 128, 64, 2, 2, 1, 10, 64, W + oActV, 4096, s1, 6,
         W + wofs(16), bd2, W + oActT, (u64)64 * 1280, 1280, 1257, 576, 64, 3, 0);
    POOL4(32, 79, W + wofs(1), W + oActT, W + oActV, 5024, 1280, 4096);
    GEMM(5, EPI_OUT, 128, 16, 4, 1, 1, 2512, 1, W + oActV, 4096, s0, 6,
         W + wofs(17), bd3, d_out, 0, 5024, 321536, 576, 3, 2, 0);
    #undef GEMM
    #undef POOL
    #undef POOL4
}

// Round 18
// 487.258 us; speedup vs baseline: 1.5978x; 1.0381x over previous
//
#include <hip/hip_runtime.h>
#include <math.h>

typedef __attribute__((ext_vector_type(8))) _Float16 half8;
typedef __attribute__((ext_vector_type(4))) _Float16 half4;
typedef __attribute__((ext_vector_type(4))) float f32x4;
typedef unsigned long long u64;

#define BK 32

#define EPI_NAT  0
#define EPI_TR   1
#define EPI_FCD  2
#define EPI_OUT  3
#define EPI_PART 4

typedef const __attribute__((address_space(1))) void* gas1;
typedef __attribute__((address_space(3))) void* las3;

__device__ __forceinline__ void gl16(const void* g, void* l) {
    __builtin_amdgcn_global_load_lds((gas1)g, (las3)l, 16, 0, 0);
}
template<int N> __device__ __forceinline__ void vwait() {
    asm volatile("s_waitcnt vmcnt(%0)" :: "n"(N) : "memory");
}
__device__ __forceinline__ void barx() {
    asm volatile("" ::: "memory");
    __builtin_amdgcn_s_barrier();
    asm volatile("" ::: "memory");
}

// ============ pool4: 256 thr, 4 waves (2x2), 64x128 tile, BK=64, 2-buf (r16 WIN) ============
__global__ __launch_bounds__(256, 3) void pool4_k(
    const _Float16* __restrict__ Aw, const _Float16* __restrict__ Bw,
    _Float16* __restrict__ Cp, int M, int Np, u64 c_rs)
{
    constexpr int LPS = 6;

    __shared__ _Float16 sA[2][64][64];
    __shared__ _Float16 sB[2][128][64];

    const int t  = threadIdx.x;
    const int m0 = blockIdx.y * 64;
    const int f0 = blockIdx.x * 128;
    const int lane = t & 63;
    const int wid  = t >> 6;
    const int wm = wid >> 1;
    const int wf = wid & 1;
    const int lm = lane & 15;
    const int lg = lane >> 4;

    f32x4 acc[2][4];
    #pragma unroll
    for (int i = 0; i < 2; ++i)
        #pragma unroll
        for (int j = 0; j < 4; ++j)
            acc[i][j] = (f32x4)0.0f;

    auto stage = [&](int buf, int ks) {
        #pragma unroll
        for (int j = 0; j < 2; ++j) {
            int c   = t + j * 256;
            int row = c >> 3;
            int ch  = (c & 7) ^ (row & 7);
            int rc  = m0 + row; if (rc >= M) rc = M - 1;
            gl16(Aw + (u64)rc * Np + ks * 64 + ch * 8,
                 (_Float16*)&sA[buf][0][0] + (u64)c * 8);
        }
        #pragma unroll
        for (int j = 0; j < 4; ++j) {
            int c   = t + j * 256;
            int row = c >> 3;
            int ch  = (c & 7) ^ (row & 7);
            gl16(Bw + (u64)(f0 + row) * Np + ks * 64 + ch * 8,
                 (_Float16*)&sB[buf][0][0] + (u64)c * 8);
        }
    };

    auto compute = [&](int buf) {
        #pragma unroll
        for (int kh = 0; kh < 2; ++kh) {
            const int ch = (kh * 4 + lg) ^ (lm & 7);
            half8 af[2], bf[4];
            #pragma unroll
            for (int i = 0; i < 2; ++i)
                af[i] = *(const half8*)&sA[buf][wm * 32 + i * 16 + lm][ch * 8];
            #pragma unroll
            for (int j = 0; j < 4; ++j)
                bf[j] = *(const half8*)&sB[buf][wf * 64 + j * 16 + lm][ch * 8];
            #pragma unroll
            for (int i = 0; i < 2; ++i)
                #pragma unroll
                for (int j = 0; j < 4; ++j)
                    acc[i][j] = __builtin_amdgcn_mfma_f32_16x16x32_f16(af[i], bf[j], acc[i][j], 0, 0, 0);
        }
    };

    const int ke = Np / 64;
    stage(0, 0);
    if (1 < ke) stage(1, 1);
    for (int ks = 0; ks < ke; ++ks) {
        if (ke - ks >= 2) vwait<LPS>();
        else              vwait<0>();
        barx();
        compute(ks & 1);
        barx();
        if (ks + 2 < ke) stage(ks & 1, ks + 2);
    }

    #pragma unroll
    for (int j = 0; j < 4; ++j) {
        int fl = f0 + wf * 64 + j * 16 + lm;
        #pragma unroll
        for (int i = 0; i < 2; ++i) {
            #pragma unroll
            for (int r = 0; r < 4; ++r) {
                int m = m0 + wm * 32 + i * 16 + lg * 4 + r;
                if (m < M)
                    Cp[(u64)m * c_rs + fl] = (_Float16)acc[i][j][r];
            }
        }
    }
}

// ============ sconv4: gather sconv on the pool4 skeleton (BK=64, 2-buf) ============
// A gathered from actV via sIdx (LDS), grid.z = batch; B = weightsT [F][Np]; EPI_TR packed.
template<int TBM, int TBF, int WM, int WF>
__global__ __launch_bounds__(256) void sconv4_k(
    const _Float16* __restrict__ Aw, u64 a_rs,
    const int* __restrict__ idx, int FiLog,
    const _Float16* __restrict__ Bw,
    const float* __restrict__ bias,
    _Float16* __restrict__ Cp, u64 c_rs, int Mp_out,
    int M, int Np, int F, int flags)
{
    constexpr int FM = TBM / WM / 16;
    constexpr int FF = TBF / WF / 16;
    constexpr int LPS = TBM / 32 + TBF / 32;

    __shared__ _Float16 sA[2][TBM][64];
    __shared__ _Float16 sB[2][TBF][64];
    __shared__ int sIdx[TBM][9];

    const int t  = threadIdx.x;
    const int b  = blockIdx.z;
    const int m0 = blockIdx.y * TBM;
    const int f0 = blockIdx.x * TBF;
    const int lane = t & 63;
    const int wid  = t >> 6;
    const int wm = wid / WF;
    const int wf = wid % WF;
    const int lm = lane & 15;
    const int lg = lane >> 4;
    const int Fi = 1 << FiLog;

    f32x4 acc[FM][FF];
    #pragma unroll
    for (int i = 0; i < FM; ++i)
        #pragma unroll
        for (int j = 0; j < FF; ++j)
            acc[i][j] = (f32x4)0.0f;

    for (int i = t; i < TBM * 9; i += 256) {
        int r = i / 9, k = i - r * 9;
        int rc = m0 + r; if (rc >= M) rc = M - 1;
        sIdx[r][k] = idx[rc * 9 + k];
    }
    __syncthreads();

    auto stage = [&](int buf, int ks) {
        #pragma unroll
        for (int j = 0; j < TBM / 32; ++j) {
            int c   = t + j * 256;
            int row = c >> 3;
            int ch  = (c & 7) ^ (row & 7);
            int col = ks * 64 + ch * 8;
            int k = col >> FiLog, fi = col & (Fi - 1);
            gl16(Aw + (u64)sIdx[row][k] * a_rs + b * Fi + fi,
                 (_Float16*)&sA[buf][0][0] + (u64)c * 8);
        }
        #pragma unroll
        for (int j = 0; j < TBF / 32; ++j) {
            int c   = t + j * 256;
            int row = c >> 3;
            int ch  = (c & 7) ^ (row & 7);
            gl16(Bw + (u64)(f0 + row) * Np + ks * 64 + ch * 8,
                 (_Float16*)&sB[buf][0][0] + (u64)c * 8);
        }
    };

    auto compute = [&](int buf) {
        #pragma unroll
        for (int kh = 0; kh < 2; ++kh) {
            const int ch = (kh * 4 + lg) ^ (lm & 7);
            half8 af[FM], bf[FF];
            #pragma unroll
            for (int i = 0; i < FM; ++i)
                af[i] = *(const half8*)&sA[buf][wm * (FM * 16) + i * 16 + lm][ch * 8];
            #pragma unroll
            for (int j = 0; j < FF; ++j)
                bf[j] = *(const half8*)&sB[buf][wf * (FF * 16) + j * 16 + lm][ch * 8];
            #pragma unroll
            for (int i = 0; i < FM; ++i)
                #pragma unroll
                for (int j = 0; j < FF; ++j)
                    acc[i][j] = __builtin_amdgcn_mfma_f32_16x16x32_f16(af[i], bf[j], acc[i][j], 0, 0, 0);
        }
    };

    const int ke = Np / 64;
    stage(0, 0);
    if (1 < ke) stage(1, 1);
    for (int ks = 0; ks < ke; ++ks) {
        if (ke - ks >= 2) vwait<LPS>();
        else              vwait<0>();
        barx();
        compute(ks & 1);
        barx();
        if (ks + 2 < ke) stage(ks & 1, ks + 2);
    }

    // EPI_TR packed half4 stores
    #pragma unroll
    for (int j = 0; j < FF; ++j) {
        int fl = f0 + wf * (FF * 16) + j * 16 + lm;
        float bv = (bias != nullptr && fl < F) ? bias[fl] : 0.f;
        #pragma unroll
        for (int i = 0; i < FM; ++i) {
            int mb = m0 + wm * (FM * 16) + i * 16 + lg * 4;
            if (fl < F && mb < Mp_out) {
                half4 o;
                #pragma unroll
                for (int r = 0; r < 4; ++r) {
                    int m = mb + r;
                    float v = acc[i][j][r] + bv;
                    if (flags & 1) v = (v > 0.f) ? v : expm1f(v);
                    o[r] = (m < M && !((flags & 2) && m == M - 1)) ? (_Float16)v : (_Float16)0.f;
                }
                *(half4*)&Cp[(u64)b * c_rs + (u64)fl * Mp_out + mb] = o;
            }
        }
    }
}

// ============ pool2 (r9): 256 thr, 4 waves (2x2), TBMx128, BK=32, 3-buf ============
template<int TBM>
__global__ __launch_bounds__(256, 3) void pool2_k(
    const _Float16* __restrict__ Aw, const _Float16* __restrict__ Bw,
    _Float16* __restrict__ Cp, int M, int Np, u64 c_rs)
{
    constexpr int FM  = TBM / 32;
    constexpr int LPS = TBM / 64 + 2;

    __shared__ _Float16 sA[3][TBM][BK];
    __shared__ _Float16 sB[3][128][BK];

    const int t  = threadIdx.x;
    const int m0 = blockIdx.y * TBM;
    const int f0 = blockIdx.x * 128;
    const int lane = t & 63;
    const int wid  = t >> 6;
    const int wm = wid >> 1;
    const int wf = wid & 1;
    const int lm = lane & 15;
    const int lg = lane >> 4;

    f32x4 acc[FM][4];
    #pragma unroll
    for (int i = 0; i < FM; ++i)
        #pragma unroll
        for (int j = 0; j < 4; ++j)
            acc[i][j] = (f32x4)0.0f;

    auto stage = [&](int buf, int ks) {
        #pragma unroll
        for (int j = 0; j < TBM / 64; ++j) {
            int c   = t + j * 256;
            int row = c >> 2;
            int sw  = ((c & 3) ^ ((row >> 1) & 3)) * 8;
            int rc  = m0 + row; if (rc >= M) rc = M - 1;
            gl16(Aw + (u64)rc * Np + ks * BK + sw,
                 (_Float16*)&sA[buf][0][0] + (u64)c * 8);
        }
        #pragma unroll
        for (int j = 0; j < 2; ++j) {
            int c   = t + j * 256;
            int row = c >> 2;
            int sw  = ((c & 3) ^ ((row >> 1) & 3)) * 8;
            gl16(Bw + (u64)(f0 + row) * Np + ks * BK + sw,
                 (_Float16*)&sB[buf][0][0] + (u64)c * 8);
        }
    };

    auto compute = [&](int buf) {
        const int sa = (lg ^ ((lm >> 1) & 3)) * 8;
        half8 af[FM], bf[4];
        #pragma unroll
        for (int i = 0; i < FM; ++i)
            af[i] = *(const half8*)&sA[buf][wm * (FM * 16) + i * 16 + lm][sa];
        #pragma unroll
        for (int j = 0; j < 4; ++j)
            bf[j] = *(const half8*)&sB[buf][wf * 64 + j * 16 + lm][sa];
        #pragma unroll
        for (int i = 0; i < FM; ++i)
            #pragma unroll
            for (int j = 0; j < 4; ++j)
                acc[i][j] = __builtin_amdgcn_mfma_f32_16x16x32_f16(af[i], bf[j], acc[i][j], 0, 0, 0);
    };

    const int ke = Np / BK;
    stage(0, 0);
    if (1 < ke) stage(1, 1);
    if (2 < ke) stage(2, 2);
    int cur = 0;
    for (int ks = 0; ks < ke; ++ks) {
        int rem = ke - ks;
        if (rem >= 3)      vwait<2 * LPS>();
        else if (rem == 2) vwait<LPS>();
        else               vwait<0>();
        barx();
        compute(cur);
        barx();
        if (ks + 3 < ke) stage(cur, ks + 3);
        cur = (cur == 2) ? 0 : cur + 1;
    }

    #pragma unroll
    for (int j = 0; j < 4; ++j) {
        int fl = f0 + wf * 64 + j * 16 + lm;
        #pragma unroll
        for (int i = 0; i < FM; ++i) {
            #pragma unroll
            for (int r = 0; r < 4; ++r) {
                int m = m0 + wm * (FM * 16) + i * 16 + lg * 4 + r;
                if (m < M)
                    Cp[(u64)m * c_rs + fl] = (_Float16)acc[i][j][r];
            }
        }
    }
}

// ============ general kernel (sconv0 / fc / Wd3) ============
// AMODE: 2 sconv0 (vectorized half4 gather, Xp4, K=64),
//        3 fc, 4 fc-enc split-K, 5 sconv rows-folded [Wd3]
template<int AMODE, int EPI, int TBM, int TBF, int WM, int WF>
__global__ __launch_bounds__(256) void gemm_k(
    const _Float16* __restrict__ Aw, u64 a_rs,
    const int* __restrict__ idx, int FiLog,
    const _Float16* __restrict__ Bw,
    const float* __restrict__ bias,
    void* __restrict__ Cp, u64 c_rs, int Mp_out,
    int M, int Np, int F, int flags, int ksp)
{
    constexpr int FM = TBM / WM / 16;
    constexpr int FF = TBF / WF / 16;
    constexpr int LPS_A = TBM / 64;
    constexpr bool BSM = (TBF < 64);
    constexpr int LPS_B = BSM ? 0 : TBF / 64;
    constexpr int LW0 = LPS_A + (BSM ? 1 : LPS_B);
    constexpr int LWX = LPS_A + LPS_B;
    constexpr int NI = (AMODE == 2) ? TBM : 2;

    __shared__ _Float16 sA[3][TBM][BK];
    __shared__ _Float16 sB[3][TBF][BK];
    __shared__ int sIdx[NI][9];

    const int t  = threadIdx.x;
    const int b  = blockIdx.z;
    const int m0 = blockIdx.y * TBM;
    const int f0 = blockIdx.x * TBF;
    const int lane = t & 63;
    const int wid  = t >> 6;
    const int wm = wid / WF;
    const int wf = wid % WF;
    const int lm = lane & 15;
    const int lg = lane >> 4;
    const int Fi = 1 << FiLog;

    f32x4 acc[FM][FF];
    #pragma unroll
    for (int i = 0; i < FM; ++i)
        #pragma unroll
        for (int j = 0; j < FF; ++j)
            acc[i][j] = (f32x4)0.0f;

    if constexpr (AMODE == 2) {
        for (int i = t; i < TBM * 9; i += 256) {
            int r = i / 9, k = i - r * 9;
            int rc = m0 + r; if (rc >= M) rc = M - 1;
            sIdx[r][k] = idx[rc * 9 + k];
        }
        __syncthreads();
    } else if constexpr (AMODE == 5) {
        if (t < 18) {
            int r = t / 9, k = t - r * 9;
            sIdx[r][k] = idx[((m0 >> 6) + r) * 9 + k];
        }
        __syncthreads();
    }

    auto stage = [&](int buf, int ks) {
        if constexpr (AMODE != 2) {
            #pragma unroll
            for (int j = 0; j < LPS_A; ++j) {
                int c   = t + j * 256;
                int row = c >> 2;
                int sw  = ((c & 3) ^ ((row >> 1) & 3)) * 8;
                int col = ks * BK + sw;
                const _Float16* src;
                if constexpr (AMODE == 3) {
                    int rc = m0 + row; if (rc >= M) rc = M - 1;
                    src = Aw + (u64)rc * Np + col;
                } else if constexpr (AMODE == 4) {
                    int k = col >> FiLog, fi = col & (Fi - 1);
                    src = Aw + (u64)k * a_rs + (m0 + row) * Fi + fi;
                } else {  // 5
                    int k = col >> FiLog, fi = col & (Fi - 1);
                    int bb = (m0 + row) & 63;
                    src = Aw + (u64)sIdx[row >> 6][k] * a_rs + bb * Fi + fi;
                }
                gl16(src, &sA[buf][row][(c & 3) * 8]);
            }
        }
        if constexpr (!BSM) {
            #pragma unroll
            for (int j = 0; j < LPS_B; ++j) {
                int c   = t + j * 256;
                int row = c >> 2;
                int sw  = ((c & 3) ^ ((row >> 1) & 3)) * 8;
                gl16(Bw + (u64)(f0 + row) * Np + ks * BK + sw, &sB[buf][row][(c & 3) * 8]);
            }
        } else {
            if (wid == 0) {
                int c   = t;
                int row = c >> 2;
                int sw  = ((c & 3) ^ ((row >> 1) & 3)) * 8;
                gl16(Bw + (u64)(f0 + row) * Np + ks * BK + sw, &sB[buf][row][(c & 3) * 8]);
            }
        }
    };

    auto compute = [&](int buf) {
        const int sa = (lg ^ ((lm >> 1) & 3)) * 8;
        half8 af[FM], bf[FF];
        #pragma unroll
        for (int i = 0; i < FM; ++i)
            af[i] = *(const half8*)&sA[buf][wm * (FM * 16) + i * 16 + lm][sa];
        #pragma unroll
        for (int j = 0; j < FF; ++j)
            bf[j] = *(const half8*)&sB[buf][wf * (FF * 16) + j * 16 + lm][sa];
        #pragma unroll
        for (int i = 0; i < FM; ++i)
            #pragma unroll
            for (int j = 0; j < FF; ++j)
                acc[i][j] = __builtin_amdgcn_mfma_f32_16x16x32_f16(af[i], bf[j], acc[i][j], 0, 0, 0);
    };

    if constexpr (AMODE == 2) {
        stage(0, 0);
        stage(1, 1);
        {
            int row = t >> 1;
            int h   = t & 1;
            #pragma unroll
            for (int cc = 0; cc < 4; ++cc) {
                int g0 = h * 8 + cc * 2;
                int g1 = g0 + 1;
                half4 lo = {(_Float16)0,(_Float16)0,(_Float16)0,(_Float16)0};
                half4 hi = lo;
                if (g0 < 9) lo = *(const half4*)(Aw + (u64)sIdx[row][g0] * a_rs + b * 4);
                if (g1 < 9) hi = *(const half4*)(Aw + (u64)sIdx[row][g1] * a_rs + b * 4);
                half8 w;
                #pragma unroll
                for (int q = 0; q < 4; ++q) { w[q] = lo[q]; w[4 + q] = hi[q]; }
                int cp = cc ^ ((row >> 1) & 3);
                *(half8*)&sA[h][row][cp * 8] = w;
            }
        }
        vwait<0>();
        __syncthreads();
        compute(0);
        compute(1);
    } else {
        int kb = 0, ke = Np / BK;
        if constexpr (AMODE == 4) { kb = b * ksp; ke = kb + ksp; }
        stage(0, kb);
        if (kb + 1 < ke) stage(1, kb + 1);
        if (kb + 2 < ke) stage(2, kb + 2);
        int cur = 0;
        for (int ks = kb; ks < ke; ++ks) {
            int rem = ke - ks;
            if (rem >= 3) {
                if constexpr (LW0 == LWX) vwait<2 * LW0>();
                else { if (wid == 0) vwait<2 * LW0>(); else vwait<2 * LWX>(); }
            } else if (rem == 2) {
                if constexpr (LW0 == LWX) vwait<LW0>();
                else { if (wid == 0) vwait<LW0>(); else vwait<LWX>(); }
            } else {
                vwait<0>();
            }
            barx();
            compute(cur);
            barx();
            if (ks + 3 < ke) stage(cur, ks + 3);
            cur = (cur == 2) ? 0 : cur + 1;
        }
    }

    if constexpr (EPI == EPI_TR) {
        #pragma unroll
        for (int j = 0; j < FF; ++j) {
            int fl = f0 + wf * (FF * 16) + j * 16 + lm;
            float bv = (bias != nullptr && fl < F) ? bias[fl] : 0.f;
            #pragma unroll
            for (int i = 0; i < FM; ++i) {
                int mb = m0 + wm * (FM * 16) + i * 16 + lg * 4;
                if (fl < F && mb < Mp_out) {
                    half4 o;
                    #pragma unroll
                    for (int r = 0; r < 4; ++r) {
                        int m = mb + r;
                        float v = acc[i][j][r] + bv;
                        if (flags & 1) v = (v > 0.f) ? v : expm1f(v);
                        o[r] = (m < M && !((flags & 2) && m == M - 1)) ? (_Float16)v : (_Float16)0.f;
                    }
                    *(half4*)&((_Float16*)Cp)[(u64)b * c_rs + (u64)fl * Mp_out + mb] = o;
                }
            }
        }
    } else {
        #pragma unroll
        for (int j = 0; j < FF; ++j) {
            int fl = f0 + wf * (FF * 16) + j * 16 + lm;
            float bv = 0.f;
            if (bias != nullptr && fl < F) bv = bias[fl];
            #pragma unroll
            for (int i = 0; i < FM; ++i) {
                #pragma unroll
                for (int r = 0; r < 4; ++r) {
                    int m = m0 + wm * (FM * 16) + i * 16 + lg * 4 + r;
                    float v = acc[i][j][r] + bv;
                    if (flags & 1) v = (v > 0.f) ? v : expm1f(v);
                    if constexpr (EPI == EPI_NAT) {
                        if (m < M && fl < F)
                            ((_Float16*)Cp)[(u64)m * c_rs + fl] = (_Float16)v;
                    } else if constexpr (EPI == EPI_FCD) {
                        if (m < M && fl < F)
                            ((_Float16*)Cp)[((u64)m * 256 + (fl & 255)) * 32 + (fl >> 8)] = (_Float16)v;
                    } else if constexpr (EPI == EPI_PART) {
                        if (m < M && fl < F)
                            ((float*)Cp)[(u64)b * c_rs + (u64)m * F + fl] = v;
                    } else {  // EPI_OUT
                        if (m < M && fl < F) {
                            int vo = m >> 6, bb = m & 63;
                            float o = ((flags & 2) && vo == Mp_out - 1) ? 0.f : v;
                            ((float*)Cp)[((u64)bb * Mp_out + vo) * 3 + fl] = o;
                        }
                    }
                }
            }
        }
    }
}

// ---- fused weight conversion ----
struct CvtPtrs { const float* p[18]; };

constexpr int CV_R[18]  = {1257,5024,315,1257,80,315,21,80,  64,64,128,256,256,5376,128,64,64,16};
constexpr int CV_N[18]  = {5024,1257,1257,315,315,80,80,21,  27,576,576,1152,5376,256,2304,1152,576,576};
constexpr int CV_NP[18] = {5120,1280,1280,320,320,96,96,32,  64,576,576,1152,5376,256,2304,1152,576,576};
constexpr int CV_F[18]  = {0,0,0,0,0,0,0,0,  64,64,128,256,256,5376,128,64,64,3};

constexpr u64 cv_elems(int i) { return (u64)CV_R[i] * CV_NP[i]; }
constexpr u64 cv_off(int i) { u64 o = 0; for (int j = 0; j < i; ++j) o += (cv_elems(j) + 255) & ~(u64)255; return o; }
constexpr int cv_blk(int i) { return (int)((cv_elems(i) + 255) >> 8); }
constexpr int cv_start(int i) { int s = 0; for (int j = 0; j < i; ++j) s += cv_blk(j); return s; }

__global__ __launch_bounds__(256) void cvt_all(CvtPtrs ps, _Float16* __restrict__ dst)
{
    const int bx = blockIdx.x, t = threadIdx.x;
    #pragma unroll
    for (int i = 0; i < 18; ++i) {
        if (bx >= cv_start(i) && bx < cv_start(i + 1)) {
            const u64 e = (u64)(bx - cv_start(i)) * 256 + t;
            if (e < cv_elems(i)) {
                const int NP = CV_NP[i], N = CV_N[i], Fo = CV_F[i];
                int row = (int)(e / (u64)NP);
                int col = (int)(e - (u64)row * NP);
                float v = 0.f;
                const float* s = ps.p[i];
                if (i == 8) {
                    int k = col >> 2, c = col & 3;
                    if (c < 3 && k < 9) v = s[(u64)(k * 3 + c) * Fo + row];
                } else if (Fo == 0) {
                    if (col < N) v = s[(u64)row * N + col];
                } else {
                    if (col < N && row < Fo) v = s[(u64)col * Fo + row];
                }
                dst[cv_off(i) + e] = (_Float16)v;
            }
        }
    }
}

__global__ void cvt_x(const float* __restrict__ src, _Float16* __restrict__ dst)
{
    int i = blockIdx.x * 256 + threadIdx.x;
    if (i >= 5024 * 256) return;
    int v = i >> 8;
    int r = i & 255;
    int b = r >> 2, c = r & 3;
    dst[i] = (c < 3) ? (_Float16)src[((u64)b * 5024 + v) * 3 + c] : (_Float16)0.f;
}

__global__ void reduce_fce(const float* __restrict__ part, const float* __restrict__ bias,
                           _Float16* __restrict__ z)
{
    int i = blockIdx.x * 256 + threadIdx.x;
    int fl = i & 255;
    float s = bias[fl];
    #pragma unroll
    for (int p = 0; p < 8; ++p) s += part[(u64)p * 16384 + i];
    z[i] = (_Float16)s;
}

extern "C" void kernel_launch(void* const* d_in, const int* in_sizes, int n_in,
                              void* d_out, int out_size, void* d_ws, size_t ws_size,
                              hipStream_t stream)
{
    const float* x  = (const float*)d_in[0];
    const int* s0 = (const int*)d_in[1];
    const int* s1 = (const int*)d_in[2];
    const int* s2 = (const int*)d_in[3];
    const int* s3 = (const int*)d_in[4];
    const float* be0 = (const float*)d_in[14];
    const float* be1 = (const float*)d_in[16];
    const float* be2 = (const float*)d_in[18];
    const float* be3 = (const float*)d_in[20];
    const float* fceb = (const float*)d_in[22];
    const float* fcdb = (const float*)d_in[24];
    const float* bd0 = (const float*)d_in[26];
    const float* bd1 = (const float*)d_in[28];
    const float* bd2 = (const float*)d_in[30];
    const float* bd3 = (const float*)d_in[32];

    _Float16* W = (_Float16*)d_ws;
    size_t off = 0;
    auto alloc = [&](size_t e) { size_t o = off; off += (e + 255) & ~(size_t)255; return o; };

    const size_t oActV = alloc((size_t)5024 * 4096);
    const size_t oActT = alloc((size_t)4096 * 5120);
    const size_t oZ    = alloc((size_t)64 * 256);
    const size_t oPart = alloc((size_t)8 * 64 * 256 * 2);
    const size_t oU3in = alloc((size_t)16384 * 32);
    const size_t oXp   = alloc((size_t)5024 * 256);
    const size_t oCvt  = alloc((size_t)(cv_off(17) + ((cv_elems(17) + 255) & ~(u64)255)));
    auto wofs = [&](int i) { return oCvt + (size_t)cv_off(i); };

    cvt_x<<<dim3(5024), 256, 0, stream>>>(x, W + oXp);
    {
        CvtPtrs ps;
        ps.p[0] = (const float*)d_in[5];
        ps.p[1] = (const float*)d_in[6];
        ps.p[2] = (const float*)d_in[7];
        ps.p[3] = (const float*)d_in[8];
        ps.p[4] = (const float*)d_in[9];
        ps.p[5] = (const float*)d_in[10];
        ps.p[6] = (const float*)d_in[11];
        ps.p[7] = (const float*)d_in[12];
        ps.p[8] = (const float*)d_in[13];
        ps.p[9] = (const float*)d_in[15];
        ps.p[10] = (const float*)d_in[17];
        ps.p[11] = (const float*)d_in[19];
        ps.p[12] = (const float*)d_in[21];
        ps.p[13] = (const float*)d_in[23];
        ps.p[14] = (const float*)d_in[25];
        ps.p[15] = (const float*)d_in[27];
        ps.p[16] = (const float*)d_in[29];
        ps.p[17] = (const float*)d_in[31];
        cvt_all<<<dim3(cv_start(18)), 256, 0, stream>>>(ps, W + oCvt);
    }
    hipMemsetAsync(W + oU3in, 0, (size_t)16384 * 32 * sizeof(_Float16), stream);

    #define GEMM(AM, EP, BM_, BF_, WM_, WF_, gx, gy, gz, Aw_, ars_, idx_, FiL_, Bw_, bias_, Cp_, crs_, Mp_, M_, Np_, F_, fl_, ksp_) \
        gemm_k<AM, EP, BM_, BF_, WM_, WF_><<<dim3(gx, gy, gz), 256, 0, stream>>>( \
            Aw_, ars_, idx_, FiL_, Bw_, bias_, Cp_, crs_, Mp_, M_, Np_, F_, fl_, ksp_)
    #define SC4(BM_, BF_, WM_, WF_, gx, gy, Aw_, ars_, idx_, FiL_, Bw_, bias_, Cp_, crs_, Mp_, M_, Np_, F_, fl_) \
        sconv4_k<BM_, BF_, WM_, WF_><<<dim3(gx, gy, 64), 256, 0, stream>>>( \
            Aw_, ars_, idx_, FiL_, Bw_, bias_, Cp_, crs_, Mp_, M_, Np_, F_, fl_)
    #define POOL(TBM_, gx, gy, Aw_, Bw_, Cp_, M_, Np_, crs_) \
        pool2_k<TBM_><<<dim3(gx, gy), 256, 0, stream>>>(Aw_, Bw_, Cp_, M_, Np_, crs_)
    #define POOL4(gx, gy, Aw_, Bw_, Cp_, M_, Np_, crs_) \
        pool4_k<<<dim3(gx, gy), 256, 0, stream>>>(Aw_, Bw_, Cp_, M_, Np_, crs_)

    // ---- encoder ----
    GEMM(2, EPI_TR, 128, 64, 2, 2, 1, 40, 64, W + oXp, 256, s0, 0,
         W + wofs(8), be0, W + oActT, (u64)64 * 5120, 5120, 5024, 64, 64, 3, 0);
    POOL4(32, 20, W + wofs(0), W + oActT, W + oActV, 1257, 5120, 4096);
    SC4(128, 64, 2, 2, 1, 10, W + oActV, 4096, s1, 6,
        W + wofs(9), be1, W + oActT, (u64)64 * 1280, 1280, 1257, 576, 64, 3);
    POOL4(32, 5, W + wofs(2), W + oActT, W + oActV, 315, 1280, 4096);
    SC4(128, 64, 2, 2, 2, 3, W + oActV, 4096, s2, 6,
        W + wofs(10), be2, W + oActT, (u64)128 * 320, 320, 315, 576, 128, 3);
    POOL4(64, 2, W + wofs(4), W + oActT, W + oActV, 80, 320, 8192);
    SC4(128, 64, 2, 2, 4, 1, W + oActV, 8192, s3, 7,
        W + wofs(11), be3, W + oActT, (u64)256 * 96, 96, 80, 1152, 256, 3);
    POOL(64, 128, 1, W + wofs(6), W + oActT, W + oActV, 21, 96, 16384);
    // ---- bottleneck ----
    GEMM(4, EPI_PART, 64, 64, 2, 2, 4, 1, 8, W + oActV, 16384, nullptr, 8,
         W + wofs(12), nullptr, W + oPart, (u64)64 * 256, 0, 64, 5376, 256, 0, 21);
    reduce_fce<<<dim3(64), 256, 0, stream>>>((const float*)(W + oPart), fceb, W + oZ);
    GEMM(3, EPI_FCD, 64, 128, 2, 2, 42, 1, 1, W + oZ, 0, nullptr, 0,
         W + wofs(13), fcdb, W + oU3in, 0, 0, 64, 256, 5376, 0, 0);
    // ---- decoder ----
    POOL(64, 128, 2, W + wofs(7), W + oU3in, W + oActV, 80, 32, 16384);
    SC4(128, 64, 2, 2, 2, 1, W + oActV, 16384, s3, 8,
        W + wofs(14), bd0, W + oActT, (u64)128 * 96, 96, 80, 2304, 128, 3);
    POOL(64, 64, 5, W + wofs(5), W + oActT, W + oActV, 315, 96, 8192);
    SC4(128, 64, 2, 2, 1, 3, W + oActV, 8192, s2, 7,
        W + wofs(15), bd1, W + oActT, (u64)64 * 320, 320, 315, 1152, 64, 3);
    POOL4(32, 20, W + wofs(3), W + oActT, W + oActV, 1257, 320, 4096);
    SC4(128, 64, 2, 2, 1, 10, W + oActV, 4096, s1, 6,
        W + wofs(16), bd2, W + oActT, (u64)64 * 1280, 1280, 1257, 576, 64, 3);
    POOL4(32, 79, W + wofs(1), W + oActT, W + oActV, 5024, 1280, 4096);
    GEMM(5, EPI_OUT, 128, 16, 4, 1, 1, 2512, 1, W + oActV, 4096, s0, 6,
         W + wofs(17), bd3, d_out, 0, 5024, 321536, 576, 3, 2, 0);
    #undef GEMM
    #undef SC4
    #undef POOL
    #undef POOL4
}